// Round 2
// baseline (704.966 us; speedup 1.0000x reference)
//
#include <hip/hip_runtime.h>

#define CN 16
#define HN 128
#define IMH 256
#define IMW 256
#define HW (IMH * IMW)

typedef __attribute__((ext_vector_type(8))) short short8;
typedef __attribute__((ext_vector_type(4))) float float4v;
typedef __attribute__((ext_vector_type(2))) unsigned int uint2v;
typedef __attribute__((ext_vector_type(4))) unsigned int uint4v;

__device__ __forceinline__ unsigned int f2bf(float f) {
    unsigned int u = __builtin_bit_cast(unsigned int, f);
    u += 0x7FFFu + ((u >> 16) & 1u);          // round-to-nearest-even
    return u >> 16;
}
// HW packed f32->bf16 (RNE, identical rounding to f2bf): 1 VALU op instead of ~10
__device__ __forceinline__ unsigned int pack2(float a, float b) {
    unsigned int r;
    asm("v_cvt_pk_bf16_f32 %0, %1, %2" : "=v"(r) : "v"(a), "v"(b));
    return r;
}

// ---------------- Weight prep: fragment-ordered bf16 weights ----------------
__global__ void nca_prep(const float* __restrict__ w1, const float* __restrict__ b1,
                         const float* __restrict__ w2,
                         unsigned short* __restrict__ a1f, unsigned short* __restrict__ b2f)
{
    int t = blockIdx.x * 256 + threadIdx.x;
    if (t < 8192) {
        int j = t & 7, lane = (t >> 3) & 63, ks = (t >> 9) & 1, mi = t >> 10;
        int hid = 16 * mi + (lane & 15);
        int k = 32 * ks + 8 * (lane >> 4) + j;
        float v = 0.f;
        if (k < 48) v = w1[hid * 48 + k];
        else if (k == 48) v = b1[hid];
        a1f[t] = (unsigned short)f2bf(v);
    }
    if (t < 2048) {
        int j = t & 7, lane = (t >> 3) & 63, ks = t >> 9;
        b2f[t] = (unsigned short)f2bf(w2[(lane & 15) * HN + 32 * ks + 8 * (lane >> 4) + j]);
    }
}

// ---------------- Kernel A: perception + MFMA MLP + update ----------------
// Block = 4 waves, processes 8 row-tiles of 4x32 pixels (32 rows x 32 cols total).
// Async-STAGE pipeline: tile it+1's global loads issued while tile it computes.
// LDS = 16384 (union) + 16384 (ybuf) + 8192 (xcT) = 40960 B exactly -> 4 blocks/CU.
__global__ __launch_bounds__(256, 4) void nca_mfma(
    const float* __restrict__ x, const float* __restrict__ upd,
    const unsigned short* __restrict__ a1f, const unsigned short* __restrict__ b2f,
    float* __restrict__ out, float* __restrict__ xn3, unsigned char* __restrict__ bm)
{
    __shared__ __align__(16) union {
        float sx[6][16][34];               // 13056 B (staging; dead after perception)
        unsigned short hb[4][16][128];     // 16384 B (per-wave h scratch, swizzled)
    } u;
    __shared__ __align__(16) unsigned short ybuf[128][64];   // 16384 B (swizzled, pitch 128B)
    __shared__ __align__(16) float xcT[16][128];             //  8192 B (x centers, XOR-swizzled)

    const int b   = blockIdx.z;
    const int j0  = blockIdx.x * 32;
    const int tid = threadIdx.x;
    const int lane = tid & 63, w = tid >> 6;
    const int l15 = lane & 15, q = lane >> 4;
    const float* xb = x + (size_t)b * CN * HW;
    const float* ub = upd + (size_t)b * HW;
    float* ob = out + (size_t)b * CN * HW;
    float* n3 = xn3 + (size_t)b * HW;

    // ---- weight fragment loads (L1/L2-hot; compiler may sink into GEMM phase) ----
    short8 a1[8][2];
#pragma unroll
    for (int mi = 0; mi < 8; ++mi)
#pragma unroll
        for (int ks = 0; ks < 2; ++ks)
            a1[mi][ks] = *(const short8*)(a1f + ((mi * 2 + ks) * 64 + lane) * 8);
    short8 b2[4];
#pragma unroll
    for (int ks = 0; ks < 4; ++ks)
        b2[ks] = *(const short8*)(b2f + (ks * 64 + lane) * 8);

    // ---- staging geometry: thread -> 12 main elements + 1 extra (tid<192) ----
    const int col    = tid & 31;
    const int rbase  = tid >> 5;           // rt = rbase + 8k, k = 0..11 covers 0..95
    const int ex_rt  = tid >> 1;           // tid<192: extra cols 32/33
    const int ex_col = 32 + (tid & 1);
    const bool xin = (blockIdx.x > 0) & (blockIdx.x < 7);

    float sreg[12];
    float sx1 = 0.f;

    auto issue_stage = [&](int i0) {
        if (xin && (i0 > 0) && (i0 < 252)) {
            const float* src = xb + (i0 - 1) * IMW + (j0 - 1);
#pragma unroll
            for (int k = 0; k < 12; ++k) {
                const int rt = rbase + 8 * k;
                sreg[k] = src[(rt & 15) * HW + (rt >> 4) * IMW + col];
            }
            if (tid < 192) sx1 = src[(ex_rt & 15) * HW + (ex_rt >> 4) * IMW + ex_col];
        } else {
#pragma unroll
            for (int k = 0; k < 12; ++k) {
                const int rt = rbase + 8 * k;
                const int rr = rt >> 4, c = rt & 15;
                const int gi = i0 + rr - 1, gj = j0 + col - 1;
                float v = 0.f;
                if ((unsigned)gi < IMH && (unsigned)gj < IMW) v = xb[c * HW + gi * IMW + gj];
                sreg[k] = v;
            }
            if (tid < 192) {
                const int rr = ex_rt >> 4, c = ex_rt & 15;
                const int gi = i0 + rr - 1, gj = j0 + ex_col - 1;
                float v = 0.f;
                if ((unsigned)gi < IMH && (unsigned)gj < IMW) v = xb[c * HW + gi * IMW + gj];
                sx1 = v;
            }
        }
    };

    issue_stage(blockIdx.y * 32);          // prologue: tile 0 loads

#pragma unroll 1
    for (int it = 0; it < 8; ++it) {
        const int i0 = blockIdx.y * 32 + it * 4;

        // ---- LDS-write staged tile (compiler inserts vmcnt wait here) ----
#pragma unroll
        for (int k = 0; k < 12; ++k) {
            const int rt = rbase + 8 * k;
            u.sx[rt >> 4][rt & 15][col] = sreg[k];
        }
        if (tid < 192) u.sx[ex_rt >> 4][ex_rt & 15][ex_col] = sx1;
        __syncthreads();                   // (a)

        // ---- prefetch next tile into regs: latency hides under percep+pack+GEMM ----
        if (it < 7) issue_stage(i0 + 4);

        // ---- preload upd for both epilogue halves ----
        float4v u4h[2];
#pragma unroll
        for (int half = 0; half < 2; ++half) {
            const int nt = 2 * w + half;
            u4h[half] = *(const float4v*)(ub + (i0 + (nt >> 1)) * IMW + j0
                                          + ((nt & 1) << 4) + (q << 2));
        }

        // ---- perception: thread = (pixel, 8-channel half) ----
        const int pix = tid & 127;
        const int ty  = pix >> 5, tx = pix & 31;
        const int cb  = (tid >> 7) << 3;   // 0 or 8 (wave-uniform)
        float v[24];
#pragma unroll
        for (int c8 = 0; c8 < 8; ++c8) {
            const int c = cb + c8;
            float a00 = u.sx[ty][c][tx],     a01 = u.sx[ty][c][tx + 1],     a02 = u.sx[ty][c][tx + 2];
            float a10 = u.sx[ty + 1][c][tx], a11 = u.sx[ty + 1][c][tx + 1], a12 = u.sx[ty + 1][c][tx + 2];
            float a20 = u.sx[ty + 2][c][tx], a21 = u.sx[ty + 2][c][tx + 1], a22 = u.sx[ty + 2][c][tx + 2];
            v[3 * c8]     = a11;
            v[3 * c8 + 1] = ((a02 - a00) + 2.f * (a12 - a10) + (a22 - a20)) * 0.125f;
            v[3 * c8 + 2] = ((a20 - a00) + 2.f * (a21 - a01) + (a22 - a02)) * 0.125f;
            xcT[c][pix ^ ((c & 7) << 2)] = a11;     // XOR-swizzled (bits 2..4)
            if (cb == 0 && c8 == 3) {
                // begin-alive: maxpool3 of x ch3 (zero-pad == -inf pad since x >= 0)
                float m0 = fmaxf(fmaxf(fmaxf(a00, a01), fmaxf(a02, a10)),
                                 fmaxf(fmaxf(a11, a12), fmaxf(fmaxf(a20, a21), a22)));
                bm[(size_t)b * HW + (i0 + ty) * IMW + (j0 + tx)] = (m0 > 0.1f) ? 1 : 0;
            }
        }
        {
            // pack 24 bf16 -> 3 swizzled 16B groups; cb==8 also writes pad groups 6,7
            unsigned int* yrow = (unsigned int*)&ybuf[pix][0];
            const int gbase = (cb >> 3) * 3;
            const int sw = pix & 7;
#pragma unroll
            for (int t = 0; t < 3; ++t) {
                uint4v g;
#pragma unroll
                for (int k = 0; k < 4; ++k) g[k] = pack2(v[8 * t + 2 * k], v[8 * t + 2 * k + 1]);
                *(uint4v*)&yrow[((gbase + t) ^ sw) << 2] = g;
            }
            if (cb == 8) {
                uint4v g6 = {0x3F80u, 0u, 0u, 0u};   // y[48] = 1.0 (bias column)
                uint4v g7 = {};
                *(uint4v*)&yrow[(6 ^ sw) << 2] = g6;
                *(uint4v*)&yrow[(7 ^ sw) << 2] = g7;
            }
        }
        __syncthreads();                   // (b)

        // ---- per wave: GEMM1-T -> h scratch -> GEMM2 -> epilogue ----
#pragma unroll
        for (int half = 0; half < 2; ++half) {
            const int nt  = 2 * w + half;
            const int row = 16 * nt + l15;
            const unsigned short* yr = &ybuf[row][0];
            const int rsw = row & 7;
            short8 y0 = *(const short8*)(yr + ((q ^ rsw) << 3));
            short8 y1 = *(const short8*)(yr + (((4 + q) ^ rsw) << 3));
            const int hsw = l15 & 7;
#pragma unroll
            for (int mi = 0; mi < 8; ++mi) {
                float4v acc = {};
                acc = __builtin_amdgcn_mfma_f32_16x16x32_bf16(a1[mi][0], y0, acc, 0, 0, 0);
                acc = __builtin_amdgcn_mfma_f32_16x16x32_bf16(a1[mi][1], y1, acc, 0, 0, 0);
                uint2v hp;
                hp[0] = pack2(fmaxf(acc[0], 0.f), fmaxf(acc[1], 0.f));
                hp[1] = pack2(fmaxf(acc[2], 0.f), fmaxf(acc[3], 0.f));
                *(uint2v*)&u.hb[w][l15][(((2 * mi + (q >> 1)) ^ hsw) << 3) + ((q & 1) << 2)] = hp;
            }
            float4v acc2 = {};
#pragma unroll
            for (int ks = 0; ks < 4; ++ks) {
                short8 hf = *(const short8*)&u.hb[w][l15][((4 * ks + q) ^ hsw) << 3];
                acc2 = __builtin_amdgcn_mfma_f32_16x16x32_bf16(hf, b2[ks], acc2, 0, 0, 0);
            }
            // epilogue: pixel p2 = 16nt+4q+r, channel = l15; 4 consecutive pixels -> dwordx4
            const int i  = i0 + (nt >> 1);
            const int jb = j0 + ((nt & 1) << 4) + (q << 2);
            float4v xc4 = *(const float4v*)&xcT[l15][(16 * nt + 4 * q) ^ ((l15 & 7) << 2)];
            float4v o;
#pragma unroll
            for (int r = 0; r < 4; ++r)
                o[r] = fmaf(acc2[r], (u4h[half][r] <= 0.5f) ? 1.f : 0.f, xc4[r]);
            *(float4v*)(ob + l15 * HW + i * IMW + jb) = o;
            if (l15 == 3) *(float4v*)(n3 + i * IMW + jb) = o;
        }
        __syncthreads();                   // (c): protect sx/hb union + ybuf + xcT
    }
}

// ---------------- Pass 2: alive masking ----------------
// alive = bm & (maxpool3(xn3) > 0.1); zero dead pixels (own pixel only).
// Full-row tiles (8x256), float4-staged.
__global__ __launch_bounds__(256) void nca_pass2(
    const float* __restrict__ xn3, const unsigned char* __restrict__ bm,
    float* __restrict__ out)
{
    __shared__ float s[10][264];           // data at col idx 4..259; halos at 3 and 260
    const int b   = blockIdx.z;
    const int i0  = blockIdx.y * 8;
    const int tid = threadIdx.x;
    const float* n3 = xn3 + (size_t)b * HW;

#pragma unroll
    for (int t = 0; t < 3; ++t) {
        const int idx = tid + 256 * t;     // 640 float4 slots: 10 rows x 64
        if (idx < 640) {
            const int r = idx >> 6, c4 = idx & 63;
            const int gi = i0 + r - 1;
            float4v vv;
            if ((unsigned)gi < IMH) vv = *(const float4v*)(n3 + gi * IMW + 4 * c4);
            else { vv[0] = vv[1] = vv[2] = vv[3] = -1e30f; }
            *(float4v*)&s[r][4 + 4 * c4] = vv;
        }
    }
    if (tid < 20) { const int r = tid >> 1; s[r][(tid & 1) ? 260 : 3] = -1e30f; }
    __syncthreads();

    const int c = tid;                     // column 0..255
    const unsigned char* bmb = bm + (size_t)b * HW + i0 * IMW + c;
    float* ob = out + (size_t)b * CN * HW;
#pragma unroll
    for (int r = 0; r < 8; ++r) {
        float m = fmaxf(fmaxf(fmaxf(s[r][c + 3], s[r][c + 4]), fmaxf(s[r][c + 5], s[r + 1][c + 3])),
                        fmaxf(fmaxf(s[r + 1][c + 4], s[r + 1][c + 5]),
                              fmaxf(fmaxf(s[r + 2][c + 3], s[r + 2][c + 4]), s[r + 2][c + 5])));
        if (!((m > 0.1f) && bmb[r * IMW])) {
            const int i = i0 + r;
#pragma unroll
            for (int ch = 0; ch < CN; ++ch)
                ob[ch * HW + i * IMW + c] = 0.f;
        }
    }
}

extern "C" void kernel_launch(void* const* d_in, const int* in_sizes, int n_in,
                              void* d_out, int out_size, void* d_ws, size_t ws_size,
                              hipStream_t stream) {
    const float* x   = (const float*)d_in[0];
    const float* upd = (const float*)d_in[1];
    const float* w1  = (const float*)d_in[2];
    const float* b1  = (const float*)d_in[3];
    const float* w2  = (const float*)d_in[4];
    float* out = (float*)d_out;

    char* ws = (char*)d_ws;
    float* xn3          = (float*)ws;                            // 8 MiB
    unsigned char* bmp  = (unsigned char*)(ws + (8u << 20));     // 2 MiB
    unsigned short* a1f = (unsigned short*)(ws + (10u << 20));   // 16 KiB
    unsigned short* b2f = a1f + 8192;                            // 4 KiB

    nca_prep<<<32, 256, 0, stream>>>(w1, b1, w2, a1f, b2f);
    nca_mfma<<<dim3(8, 8, 32), 256, 0, stream>>>(x, upd, a1f, b2f, out, xn3, bmp);
    nca_pass2<<<dim3(1, 32, 32), 256, 0, stream>>>(xn3, bmp, out);
}

// Round 3
// 700.607 us; speedup vs baseline: 1.0062x; 1.0062x over previous
//
#include <hip/hip_runtime.h>

#define CN 16
#define HN 128
#define IMH 256
#define IMW 256
#define HW (IMH * IMW)

typedef __attribute__((ext_vector_type(8))) short short8;
typedef __attribute__((ext_vector_type(4))) float float4v;
typedef __attribute__((ext_vector_type(2))) unsigned int uint2v;
typedef __attribute__((ext_vector_type(4))) unsigned int uint4v;

__device__ __forceinline__ unsigned int f2bf(float f) {
    unsigned int u = __builtin_bit_cast(unsigned int, f);
    u += 0x7FFFu + ((u >> 16) & 1u);          // round-to-nearest-even
    return u >> 16;
}
// HW packed f32->bf16 (RNE, identical rounding to f2bf): 1 VALU op instead of ~10
__device__ __forceinline__ unsigned int pack2(float a, float b) {
    unsigned int r;
    asm("v_cvt_pk_bf16_f32 %0, %1, %2" : "=v"(r) : "v"(a), "v"(b));
    return r;
}

// ---------------- Weight prep: fragment-ordered bf16 weights ----------------
__global__ void nca_prep(const float* __restrict__ w1, const float* __restrict__ b1,
                         const float* __restrict__ w2,
                         unsigned short* __restrict__ a1f, unsigned short* __restrict__ b2f)
{
    int t = blockIdx.x * 256 + threadIdx.x;
    if (t < 8192) {
        int j = t & 7, lane = (t >> 3) & 63, ks = (t >> 9) & 1, mi = t >> 10;
        int hid = 16 * mi + (lane & 15);
        int k = 32 * ks + 8 * (lane >> 4) + j;
        float v = 0.f;
        if (k < 48) v = w1[hid * 48 + k];
        else if (k == 48) v = b1[hid];
        a1f[t] = (unsigned short)f2bf(v);
    }
    if (t < 2048) {
        int j = t & 7, lane = (t >> 3) & 63, ks = t >> 9;
        b2f[t] = (unsigned short)f2bf(w2[(lane & 15) * HN + 32 * ks + 8 * (lane >> 4) + j]);
    }
}

// ---------------- Kernel A: perception + MFMA MLP + update ----------------
// Block = 4 waves, processes 8 row-tiles of 4x32 pixels (32 rows x 32 cols total).
// Async-STAGE pipeline: tile it+1's global loads issued while tile it computes.
// LDS = 16384 (union) + 16384 (ybuf) + 8192 (xcT) = 40960 B exactly -> 4 blocks/CU.
__global__ __launch_bounds__(256, 4) void nca_mfma(
    const float* __restrict__ x, const float* __restrict__ upd,
    const unsigned short* __restrict__ a1f, const unsigned short* __restrict__ b2f,
    float* __restrict__ out, float* __restrict__ xn3, unsigned char* __restrict__ bm)
{
    __shared__ __align__(16) union {
        float sx[6][16][34];               // 13056 B (staging; dead after perception)
        unsigned short hb[4][16][128];     // 16384 B (per-wave h scratch, swizzled)
    } u;
    __shared__ __align__(16) unsigned short ybuf[128][64];   // 16384 B (swizzled, pitch 128B)
    __shared__ __align__(16) float xcT[16][128];             //  8192 B (x centers, XOR-swizzled)

    const int b   = blockIdx.z;
    const int j0  = blockIdx.x * 32;
    const int tid = threadIdx.x;
    const int lane = tid & 63, w = tid >> 6;
    const int l15 = lane & 15, q = lane >> 4;
    const float* xb = x + (size_t)b * CN * HW;
    const float* ub = upd + (size_t)b * HW;
    float* ob = out + (size_t)b * CN * HW;
    float* n3 = xn3 + (size_t)b * HW;

    // ---- weight fragment loads (L1/L2-hot; compiler may sink into GEMM phase) ----
    short8 a1[8][2];
#pragma unroll
    for (int mi = 0; mi < 8; ++mi)
#pragma unroll
        for (int ks = 0; ks < 2; ++ks)
            a1[mi][ks] = *(const short8*)(a1f + ((mi * 2 + ks) * 64 + lane) * 8);
    short8 b2[4];
#pragma unroll
    for (int ks = 0; ks < 4; ++ks)
        b2[ks] = *(const short8*)(b2f + (ks * 64 + lane) * 8);

    // ---- staging geometry: thread -> 12 main elements + 1 extra (tid<192) ----
    const int col    = tid & 31;
    const int rbase  = tid >> 5;           // rt = rbase + 8k, k = 0..11 covers 0..95
    const int ex_rt  = tid >> 1;           // tid<192: extra cols 32/33
    const int ex_col = 32 + (tid & 1);
    const bool xin = (blockIdx.x > 0) & (blockIdx.x < 7);

    float sreg[12];
    float sx1 = 0.f;

    auto issue_stage = [&](int i0) {
        if (xin && (i0 > 0) && (i0 < 252)) {
            const float* src = xb + (i0 - 1) * IMW + (j0 - 1);
#pragma unroll
            for (int k = 0; k < 12; ++k) {
                const int rt = rbase + 8 * k;
                sreg[k] = src[(rt & 15) * HW + (rt >> 4) * IMW + col];
            }
            if (tid < 192) sx1 = src[(ex_rt & 15) * HW + (ex_rt >> 4) * IMW + ex_col];
        } else {
#pragma unroll
            for (int k = 0; k < 12; ++k) {
                const int rt = rbase + 8 * k;
                const int rr = rt >> 4, c = rt & 15;
                const int gi = i0 + rr - 1, gj = j0 + col - 1;
                float v = 0.f;
                if ((unsigned)gi < IMH && (unsigned)gj < IMW) v = xb[c * HW + gi * IMW + gj];
                sreg[k] = v;
            }
            if (tid < 192) {
                const int rr = ex_rt >> 4, c = ex_rt & 15;
                const int gi = i0 + rr - 1, gj = j0 + ex_col - 1;
                float v = 0.f;
                if ((unsigned)gi < IMH && (unsigned)gj < IMW) v = xb[c * HW + gi * IMW + gj];
                sx1 = v;
            }
        }
    };

    issue_stage(blockIdx.y * 32);          // prologue: tile 0 loads

#pragma unroll 1
    for (int it = 0; it < 8; ++it) {
        const int i0 = blockIdx.y * 32 + it * 4;

        // ---- LDS-write staged tile (compiler inserts vmcnt wait here) ----
#pragma unroll
        for (int k = 0; k < 12; ++k) {
            const int rt = rbase + 8 * k;
            u.sx[rt >> 4][rt & 15][col] = sreg[k];
        }
        if (tid < 192) u.sx[ex_rt >> 4][ex_rt & 15][ex_col] = sx1;
        __syncthreads();                   // (a)

        // ---- prefetch next tile into regs: latency hides under percep+pack+GEMM ----
        if (it < 7) issue_stage(i0 + 4);

        // ---- preload upd for both epilogue halves ----
        float4v u4h[2];
#pragma unroll
        for (int half = 0; half < 2; ++half) {
            const int nt = 2 * w + half;
            u4h[half] = *(const float4v*)(ub + (i0 + (nt >> 1)) * IMW + j0
                                          + ((nt & 1) << 4) + (q << 2));
        }

        // ---- perception: thread = (pixel, 8-channel half) ----
        const int pix = tid & 127;
        const int ty  = pix >> 5, tx = pix & 31;
        const int cb  = (tid >> 7) << 3;   // 0 or 8 (wave-uniform)
        float v[24];
#pragma unroll
        for (int c8 = 0; c8 < 8; ++c8) {
            const int c = cb + c8;
            float a00 = u.sx[ty][c][tx],     a01 = u.sx[ty][c][tx + 1],     a02 = u.sx[ty][c][tx + 2];
            float a10 = u.sx[ty + 1][c][tx], a11 = u.sx[ty + 1][c][tx + 1], a12 = u.sx[ty + 1][c][tx + 2];
            float a20 = u.sx[ty + 2][c][tx], a21 = u.sx[ty + 2][c][tx + 1], a22 = u.sx[ty + 2][c][tx + 2];
            v[3 * c8]     = a11;
            v[3 * c8 + 1] = ((a02 - a00) + 2.f * (a12 - a10) + (a22 - a20)) * 0.125f;
            v[3 * c8 + 2] = ((a20 - a00) + 2.f * (a21 - a01) + (a22 - a02)) * 0.125f;
            xcT[c][pix ^ ((c & 7) << 2)] = a11;     // XOR-swizzled (bits 2..4)
            if (cb == 0 && c8 == 3) {
                // begin-alive: maxpool3 of x ch3 (zero-pad == -inf pad since x >= 0)
                float m0 = fmaxf(fmaxf(fmaxf(a00, a01), fmaxf(a02, a10)),
                                 fmaxf(fmaxf(a11, a12), fmaxf(fmaxf(a20, a21), a22)));
                bm[(size_t)b * HW + (i0 + ty) * IMW + (j0 + tx)] = (m0 > 0.1f) ? 1 : 0;
            }
        }
        {
            // pack 24 bf16 -> 3 swizzled 16B groups; cb==8 also writes pad groups 6,7
            unsigned int* yrow = (unsigned int*)&ybuf[pix][0];
            const int gbase = (cb >> 3) * 3;
            const int sw = pix & 7;
#pragma unroll
            for (int t = 0; t < 3; ++t) {
                uint4v g;
#pragma unroll
                for (int k = 0; k < 4; ++k) g[k] = pack2(v[8 * t + 2 * k], v[8 * t + 2 * k + 1]);
                *(uint4v*)&yrow[((gbase + t) ^ sw) << 2] = g;
            }
            if (cb == 8) {
                uint4v g6 = {0x3F80u, 0u, 0u, 0u};   // y[48] = 1.0 (bias column)
                uint4v g7 = {};
                *(uint4v*)&yrow[(6 ^ sw) << 2] = g6;
                *(uint4v*)&yrow[(7 ^ sw) << 2] = g7;
            }
        }
        __syncthreads();                   // (b)

        // ---- per wave: GEMM1-T -> h scratch -> GEMM2 -> epilogue ----
#pragma unroll
        for (int half = 0; half < 2; ++half) {
            const int nt  = 2 * w + half;
            const int row = 16 * nt + l15;
            const unsigned short* yr = &ybuf[row][0];
            const int rsw = row & 7;
            short8 y0 = *(const short8*)(yr + ((q ^ rsw) << 3));
            short8 y1 = *(const short8*)(yr + (((4 + q) ^ rsw) << 3));
            const int hsw = l15 & 7;
#pragma unroll
            for (int mi = 0; mi < 8; ++mi) {
                float4v acc = {};
                acc = __builtin_amdgcn_mfma_f32_16x16x32_bf16(a1[mi][0], y0, acc, 0, 0, 0);
                acc = __builtin_amdgcn_mfma_f32_16x16x32_bf16(a1[mi][1], y1, acc, 0, 0, 0);
                uint2v hp;
                hp[0] = pack2(fmaxf(acc[0], 0.f), fmaxf(acc[1], 0.f));
                hp[1] = pack2(fmaxf(acc[2], 0.f), fmaxf(acc[3], 0.f));
                *(uint2v*)&u.hb[w][l15][(((2 * mi + (q >> 1)) ^ hsw) << 3) + ((q & 1) << 2)] = hp;
            }
            float4v acc2 = {};
#pragma unroll
            for (int ks = 0; ks < 4; ++ks) {
                short8 hf = *(const short8*)&u.hb[w][l15][((4 * ks + q) ^ hsw) << 3];
                acc2 = __builtin_amdgcn_mfma_f32_16x16x32_bf16(hf, b2[ks], acc2, 0, 0, 0);
            }
            // epilogue: pixel p2 = 16nt+4q+r, channel = l15; 4 consecutive pixels -> dwordx4
            const int i  = i0 + (nt >> 1);
            const int jb = j0 + ((nt & 1) << 4) + (q << 2);
            float4v xc4 = *(const float4v*)&xcT[l15][(16 * nt + 4 * q) ^ ((l15 & 7) << 2)];
            float4v o;
#pragma unroll
            for (int r = 0; r < 4; ++r)
                o[r] = fmaf(acc2[r], (u4h[half][r] <= 0.5f) ? 1.f : 0.f, xc4[r]);
            *(float4v*)(ob + l15 * HW + i * IMW + jb) = o;
            if (l15 == 3) *(float4v*)(n3 + i * IMW + jb) = o;
        }
        __syncthreads();                   // (c): protect sx/hb union + ybuf + xcT
    }
}

// ---------------- Pass 2: alive masking ----------------
// alive = bm & (maxpool3(xn3) > 0.1); zero dead pixels (own pixel only).
// Full-row tiles (8x256), float4-staged.
__global__ __launch_bounds__(256) void nca_pass2(
    const float* __restrict__ xn3, const unsigned char* __restrict__ bm,
    float* __restrict__ out)
{
    __shared__ float s[10][264];           // data at col idx 4..259; halos at 3 and 260
    const int b   = blockIdx.z;
    const int i0  = blockIdx.y * 8;
    const int tid = threadIdx.x;
    const float* n3 = xn3 + (size_t)b * HW;

#pragma unroll
    for (int t = 0; t < 3; ++t) {
        const int idx = tid + 256 * t;     // 640 float4 slots: 10 rows x 64
        if (idx < 640) {
            const int r = idx >> 6, c4 = idx & 63;
            const int gi = i0 + r - 1;
            float4v vv;
            if ((unsigned)gi < IMH) vv = *(const float4v*)(n3 + gi * IMW + 4 * c4);
            else { vv[0] = vv[1] = vv[2] = vv[3] = -1e30f; }
            *(float4v*)&s[r][4 + 4 * c4] = vv;
        }
    }
    if (tid < 20) { const int r = tid >> 1; s[r][(tid & 1) ? 260 : 3] = -1e30f; }
    __syncthreads();

    const int c = tid;                     // column 0..255
    const unsigned char* bmb = bm + (size_t)b * HW + i0 * IMW + c;
    float* ob = out + (size_t)b * CN * HW;
#pragma unroll
    for (int r = 0; r < 8; ++r) {
        float m = fmaxf(fmaxf(fmaxf(s[r][c + 3], s[r][c + 4]), fmaxf(s[r][c + 5], s[r + 1][c + 3])),
                        fmaxf(fmaxf(s[r + 1][c + 4], s[r + 1][c + 5]),
                              fmaxf(fmaxf(s[r + 2][c + 3], s[r + 2][c + 4]), s[r + 2][c + 5])));
        if (!((m > 0.1f) && bmb[r * IMW])) {
            const int i = i0 + r;
#pragma unroll
            for (int ch = 0; ch < CN; ++ch)
                ob[ch * HW + i * IMW + c] = 0.f;
        }
    }
}

extern "C" void kernel_launch(void* const* d_in, const int* in_sizes, int n_in,
                              void* d_out, int out_size, void* d_ws, size_t ws_size,
                              hipStream_t stream) {
    const float* x   = (const float*)d_in[0];
    const float* upd = (const float*)d_in[1];
    const float* w1  = (const float*)d_in[2];
    const float* b1  = (const float*)d_in[3];
    const float* w2  = (const float*)d_in[4];
    float* out = (float*)d_out;

    char* ws = (char*)d_ws;
    float* xn3          = (float*)ws;                            // 8 MiB
    unsigned char* bmp  = (unsigned char*)(ws + (8u << 20));     // 2 MiB
    unsigned short* a1f = (unsigned short*)(ws + (10u << 20));   // 16 KiB
    unsigned short* b2f = a1f + 8192;                            // 4 KiB

    nca_prep<<<32, 256, 0, stream>>>(w1, b1, w2, a1f, b2f);
    nca_mfma<<<dim3(8, 8, 32), 256, 0, stream>>>(x, upd, a1f, b2f, out, xn3, bmp);
    nca_pass2<<<dim3(1, 32, 32), 256, 0, stream>>>(xn3, bmp, out);
}

// Round 4
// 657.209 us; speedup vs baseline: 1.0727x; 1.0660x over previous
//
#include <hip/hip_runtime.h>

#define CN 16
#define HN 128
#define IMH 256
#define IMW 256
#define HW (IMH * IMW)

typedef __attribute__((ext_vector_type(8))) short short8;
typedef __attribute__((ext_vector_type(4))) float float4v;
typedef __attribute__((ext_vector_type(2))) unsigned int uint2v;
typedef __attribute__((ext_vector_type(4))) unsigned int uint4v;

__device__ __forceinline__ unsigned int f2bf(float f) {
    unsigned int u = __builtin_bit_cast(unsigned int, f);
    u += 0x7FFFu + ((u >> 16) & 1u);          // round-to-nearest-even
    return u >> 16;
}
// HW packed f32->bf16 (RNE, identical rounding to f2bf): 1 VALU op instead of ~10
__device__ __forceinline__ unsigned int pack2(float a, float b) {
    unsigned int r;
    asm("v_cvt_pk_bf16_f32 %0, %1, %2" : "=v"(r) : "v"(a), "v"(b));
    return r;
}

// ---------------- Weight prep: fragment-ordered bf16 weights ----------------
__global__ void nca_prep(const float* __restrict__ w1, const float* __restrict__ b1,
                         const float* __restrict__ w2,
                         unsigned short* __restrict__ a1f, unsigned short* __restrict__ b2f)
{
    int t = blockIdx.x * 256 + threadIdx.x;
    if (t < 8192) {
        int j = t & 7, lane = (t >> 3) & 63, ks = (t >> 9) & 1, mi = t >> 10;
        int hid = 16 * mi + (lane & 15);
        int k = 32 * ks + 8 * (lane >> 4) + j;
        float v = 0.f;
        if (k < 48) v = w1[hid * 48 + k];
        else if (k == 48) v = b1[hid];
        a1f[t] = (unsigned short)f2bf(v);
    }
    if (t < 2048) {
        int j = t & 7, lane = (t >> 3) & 63, ks = t >> 9;
        b2f[t] = (unsigned short)f2bf(w2[(lane & 15) * HN + 32 * ks + 8 * (lane >> 4) + j]);
    }
}

// ---------------- Kernel A: perception + MFMA MLP + update ----------------
// 128 pixels/block (4x32), 256 threads = 4 waves. Wave w owns pixels 32w..32w+31.
// LDS = 16384 (sx/hb union) + 16384 (ybuf) = 32768 B exactly -> 5 blocks/CU (160 KiB).
// Grid 8x64x32 = 16384 blocks: this fine-grained layout IS the L2 blocking scheme
// (R3 lesson: coarser tiles -> 6x HBM over-fetch from per-XCD L2 thrash).
__global__ __launch_bounds__(256, 5) void nca_mfma(
    const float* __restrict__ x, const float* __restrict__ upd,
    const unsigned short* __restrict__ a1f, const unsigned short* __restrict__ b2f,
    float* __restrict__ out, float* __restrict__ xn3, unsigned char* __restrict__ bm)
{
    __shared__ __align__(16) union {
        float sx[6][16][34];               // 13056 B (staging; dead after perception)
        unsigned short hb[4][16][128];     // 16384 B (per-wave h scratch, swizzled)
    } u;
    __shared__ __align__(16) unsigned short ybuf[128][64];   // 16384 B (swizzled, pitch 128B)

    const int b   = blockIdx.z;
    const int i0  = blockIdx.y * 4;
    const int j0  = blockIdx.x * 32;
    const int tid = threadIdx.x;
    const int lane = tid & 63, w = tid >> 6;
    const int l15 = lane & 15, q = lane >> 4;
    const float* xb = x + (size_t)b * CN * HW;
    const float* ub = upd + (size_t)b * HW;

    // ---- staging geometry: thread -> 12 main elements + 1 extra (tid<192) ----
    const int col    = tid & 31;
    const int rbase  = tid >> 5;
    const int ex_rt  = tid >> 1;
    const int ex_col = 32 + (tid & 1);
    const bool interior = (blockIdx.y > 0) & (blockIdx.y < 63) & (blockIdx.x > 0) & (blockIdx.x < 7);

    // ---- issue stage loads into regs FIRST (HBM/L2 latency starts now) ----
    float sreg[12];
    float sx1 = 0.f;
    if (interior) {
        const float* src = xb + (i0 - 1) * IMW + (j0 - 1);
#pragma unroll
        for (int k = 0; k < 12; ++k) {
            const int rt = rbase + 8 * k;
            sreg[k] = src[(rt & 15) * HW + (rt >> 4) * IMW + col];
        }
        if (tid < 192) sx1 = src[(ex_rt & 15) * HW + (ex_rt >> 4) * IMW + ex_col];
    } else {
#pragma unroll
        for (int k = 0; k < 12; ++k) {
            const int rt = rbase + 8 * k;
            const int rr = rt >> 4, c = rt & 15;
            const int gi = i0 + rr - 1, gj = j0 + col - 1;
            float v = 0.f;
            if ((unsigned)gi < IMH && (unsigned)gj < IMW) v = xb[c * HW + gi * IMW + gj];
            sreg[k] = v;
        }
        if (tid < 192) {
            const int rr = ex_rt >> 4, c = ex_rt & 15;
            const int gi = i0 + rr - 1, gj = j0 + ex_col - 1;
            float v = 0.f;
            if ((unsigned)gi < IMH && (unsigned)gj < IMW) v = xb[c * HW + gi * IMW + gj];
            sx1 = v;
        }
    }

    // ---- preload upd (HBM-cold): latency hides under perception + GEMM1 ----
    float4v u4h[2];
#pragma unroll
    for (int half = 0; half < 2; ++half) {
        const int nt = 2 * w + half;
        u4h[half] = *(const float4v*)(ub + (i0 + (nt >> 1)) * IMW + j0
                                      + ((nt & 1) << 4) + (q << 2));
    }

    // ---- weight fragment loads (L1/L2-hot; compiler sinks to use site) ----
    short8 a1[8][2];
#pragma unroll
    for (int mi = 0; mi < 8; ++mi)
#pragma unroll
        for (int ks = 0; ks < 2; ++ks)
            a1[mi][ks] = *(const short8*)(a1f + ((mi * 2 + ks) * 64 + lane) * 8);
    short8 b2[4];
#pragma unroll
    for (int ks = 0; ks < 4; ++ks)
        b2[ks] = *(const short8*)(b2f + (ks * 64 + lane) * 8);

    // ---- LDS-write staged tile (counted vmcnt wait on stage loads only) ----
#pragma unroll
    for (int k = 0; k < 12; ++k) {
        const int rt = rbase + 8 * k;
        u.sx[rt >> 4][rt & 15][col] = sreg[k];
    }
    if (tid < 192) u.sx[ex_rt >> 4][ex_rt & 15][ex_col] = sx1;
    __syncthreads();

    // ---- perception: thread = (pixel, 8-channel half) ----
    const int pix = tid & 127;
    const int ty  = pix >> 5, tx = pix & 31;
    const int cb  = (tid >> 7) << 3;       // 0 or 8 (wave-uniform)
    float v[24];
#pragma unroll
    for (int c8 = 0; c8 < 8; ++c8) {
        const int c = cb + c8;
        float a00 = u.sx[ty][c][tx],     a01 = u.sx[ty][c][tx + 1],     a02 = u.sx[ty][c][tx + 2];
        float a10 = u.sx[ty + 1][c][tx], a11 = u.sx[ty + 1][c][tx + 1], a12 = u.sx[ty + 1][c][tx + 2];
        float a20 = u.sx[ty + 2][c][tx], a21 = u.sx[ty + 2][c][tx + 1], a22 = u.sx[ty + 2][c][tx + 2];
        v[3 * c8]     = a11;
        v[3 * c8 + 1] = ((a02 - a00) + 2.f * (a12 - a10) + (a22 - a20)) * 0.125f;
        v[3 * c8 + 2] = ((a20 - a00) + 2.f * (a21 - a01) + (a22 - a02)) * 0.125f;
        if (cb == 0 && c8 == 3) {
            // begin-alive: maxpool3 of x ch3 (zero-pad == -inf pad since x >= 0)
            float m0 = fmaxf(fmaxf(fmaxf(a00, a01), fmaxf(a02, a10)),
                             fmaxf(fmaxf(a11, a12), fmaxf(fmaxf(a20, a21), a22)));
            bm[(size_t)b * HW + (i0 + ty) * IMW + (j0 + tx)] = (m0 > 0.1f) ? 1 : 0;
        }
    }
    {
        // pack 24 bf16 -> 3 swizzled 16B groups; cb==8 also writes pad groups 6,7
        unsigned int* yrow = (unsigned int*)&ybuf[pix][0];
        const int gbase = (cb >> 3) * 3;
        const int sw = pix & 7;
#pragma unroll
        for (int t = 0; t < 3; ++t) {
            uint4v g;
#pragma unroll
            for (int k = 0; k < 4; ++k) g[k] = pack2(v[8 * t + 2 * k], v[8 * t + 2 * k + 1]);
            *(uint4v*)&yrow[((gbase + t) ^ sw) << 2] = g;
        }
        if (cb == 8) {
            uint4v g6 = {0x3F80u, 0u, 0u, 0u};   // y[48] = 1.0 (bias column)
            uint4v g7 = {};
            *(uint4v*)&yrow[(6 ^ sw) << 2] = g6;
            *(uint4v*)&yrow[(7 ^ sw) << 2] = g7;
        }
    }
    __syncthreads();

    // ---- per wave: GEMM1-T (all 128 hid x 16 pix) -> h scratch -> GEMM2 -> epilogue ----
    float* ob = out + (size_t)b * CN * HW;
    float* n3 = xn3 + (size_t)b * HW;
#pragma unroll
    for (int half = 0; half < 2; ++half) {
        const int nt  = 2 * w + half;
        const int row = 16 * nt + l15;
        const unsigned short* yr = &ybuf[row][0];
        const int rsw = row & 7;
        short8 y0 = *(const short8*)(yr + ((q ^ rsw) << 3));
        short8 y1 = *(const short8*)(yr + (((4 + q) ^ rsw) << 3));
        const int hsw = l15 & 7;
#pragma unroll
        for (int mi = 0; mi < 8; ++mi) {
            float4v acc = {};
            acc = __builtin_amdgcn_mfma_f32_16x16x32_bf16(a1[mi][0], y0, acc, 0, 0, 0);
            acc = __builtin_amdgcn_mfma_f32_16x16x32_bf16(a1[mi][1], y1, acc, 0, 0, 0);
            uint2v hp;
            hp[0] = pack2(fmaxf(acc[0], 0.f), fmaxf(acc[1], 0.f));
            hp[1] = pack2(fmaxf(acc[2], 0.f), fmaxf(acc[3], 0.f));
            // logical col 16mi+4q -> group 2mi+(q>>1), offset 4(q&1); XOR-swizzled
            *(uint2v*)&u.hb[w][l15][(((2 * mi + (q >> 1)) ^ hsw) << 3) + ((q & 1) << 2)] = hp;
        }
        float4v acc2 = {};
#pragma unroll
        for (int ks = 0; ks < 4; ++ks) {
            short8 hf = *(const short8*)&u.hb[w][l15][((4 * ks + q) ^ hsw) << 3];
            acc2 = __builtin_amdgcn_mfma_f32_16x16x32_bf16(hf, b2[ks], acc2, 0, 0, 0);
        }
        // epilogue: pixel p2 = 16nt+4q+r, channel = l15; 4 consecutive pixels -> dwordx4
        // x center re-read from global (lines just staged by this block -> L1/L2-hot);
        // replaces the 8 KiB xcT LDS buffer (what unlocked 5 blocks/CU).
        const int i  = i0 + (nt >> 1);
        const int jb = j0 + ((nt & 1) << 4) + (q << 2);
        float4v xc4 = *(const float4v*)(xb + l15 * HW + i * IMW + jb);
        float4v o;
#pragma unroll
        for (int r = 0; r < 4; ++r)
            o[r] = fmaf(acc2[r], (u4h[half][r] <= 0.5f) ? 1.f : 0.f, xc4[r]);
        *(float4v*)(ob + l15 * HW + i * IMW + jb) = o;
        if (l15 == 3) *(float4v*)(n3 + i * IMW + jb) = o;
    }
}

// ---------------- Pass 2: alive masking ----------------
// alive = bm & (maxpool3(xn3) > 0.1); zero dead pixels (own pixel only).
// Full-row tiles (8x256), float4-staged.
__global__ __launch_bounds__(256) void nca_pass2(
    const float* __restrict__ xn3, const unsigned char* __restrict__ bm,
    float* __restrict__ out)
{
    __shared__ float s[10][264];           // data at col idx 4..259; halos at 3 and 260
    const int b   = blockIdx.z;
    const int i0  = blockIdx.y * 8;
    const int tid = threadIdx.x;
    const float* n3 = xn3 + (size_t)b * HW;

#pragma unroll
    for (int t = 0; t < 3; ++t) {
        const int idx = tid + 256 * t;     // 640 float4 slots: 10 rows x 64
        if (idx < 640) {
            const int r = idx >> 6, c4 = idx & 63;
            const int gi = i0 + r - 1;
            float4v vv;
            if ((unsigned)gi < IMH) vv = *(const float4v*)(n3 + gi * IMW + 4 * c4);
            else { vv[0] = vv[1] = vv[2] = vv[3] = -1e30f; }
            *(float4v*)&s[r][4 + 4 * c4] = vv;
        }
    }
    if (tid < 20) { const int r = tid >> 1; s[r][(tid & 1) ? 260 : 3] = -1e30f; }
    __syncthreads();

    const int c = tid;                     // column 0..255
    const unsigned char* bmb = bm + (size_t)b * HW + i0 * IMW + c;
    float* ob = out + (size_t)b * CN * HW;
#pragma unroll
    for (int r = 0; r < 8; ++r) {
        float m = fmaxf(fmaxf(fmaxf(s[r][c + 3], s[r][c + 4]), fmaxf(s[r][c + 5], s[r + 1][c + 3])),
                        fmaxf(fmaxf(s[r + 1][c + 4], s[r + 1][c + 5]),
                              fmaxf(fmaxf(s[r + 2][c + 3], s[r + 2][c + 4]), s[r + 2][c + 5])));
        if (!((m > 0.1f) && bmb[r * IMW])) {
            const int i = i0 + r;
#pragma unroll
            for (int ch = 0; ch < CN; ++ch)
                ob[ch * HW + i * IMW + c] = 0.f;
        }
    }
}

extern "C" void kernel_launch(void* const* d_in, const int* in_sizes, int n_in,
                              void* d_out, int out_size, void* d_ws, size_t ws_size,
                              hipStream_t stream) {
    const float* x   = (const float*)d_in[0];
    const float* upd = (const float*)d_in[1];
    const float* w1  = (const float*)d_in[2];
    const float* b1  = (const float*)d_in[3];
    const float* w2  = (const float*)d_in[4];
    float* out = (float*)d_out;

    char* ws = (char*)d_ws;
    float* xn3          = (float*)ws;                            // 8 MiB
    unsigned char* bmp  = (unsigned char*)(ws + (8u << 20));     // 2 MiB
    unsigned short* a1f = (unsigned short*)(ws + (10u << 20));   // 16 KiB
    unsigned short* b2f = a1f + 8192;                            // 4 KiB

    nca_prep<<<32, 256, 0, stream>>>(w1, b1, w2, a1f, b2f);
    nca_mfma<<<dim3(8, 64, 32), 256, 0, stream>>>(x, upd, a1f, b2f, out, xn3, bmp);
    nca_pass2<<<dim3(1, 32, 32), 256, 0, stream>>>(xn3, bmp, out);
}

// Round 5
// 454.209 us; speedup vs baseline: 1.5521x; 1.4469x over previous
//
#include <hip/hip_runtime.h>

#define CN 16
#define HN 128
#define IMH 256
#define IMW 256
#define HW (IMH * IMW)

typedef __attribute__((ext_vector_type(8))) short short8;
typedef __attribute__((ext_vector_type(4))) float float4v;
typedef __attribute__((ext_vector_type(2))) unsigned int uint2v;
typedef __attribute__((ext_vector_type(4))) unsigned int uint4v;

__device__ __forceinline__ unsigned int f2bf(float f) {
    unsigned int u = __builtin_bit_cast(unsigned int, f);
    u += 0x7FFFu + ((u >> 16) & 1u);          // round-to-nearest-even
    return u >> 16;
}
// HW packed f32->bf16 (RNE, identical rounding to f2bf): 1 VALU op instead of ~10
__device__ __forceinline__ unsigned int pack2(float a, float b) {
    unsigned int r;
    asm("v_cvt_pk_bf16_f32 %0, %1, %2" : "=v"(r) : "v"(a), "v"(b));
    return r;
}

// ---------------- Weight prep: fragment-ordered bf16 weights ----------------
__global__ void nca_prep(const float* __restrict__ w1, const float* __restrict__ b1,
                         const float* __restrict__ w2,
                         unsigned short* __restrict__ a1f, unsigned short* __restrict__ b2f)
{
    int t = blockIdx.x * 256 + threadIdx.x;
    if (t < 8192) {
        int j = t & 7, lane = (t >> 3) & 63, ks = (t >> 9) & 1, mi = t >> 10;
        int hid = 16 * mi + (lane & 15);
        int k = 32 * ks + 8 * (lane >> 4) + j;
        float v = 0.f;
        if (k < 48) v = w1[hid * 48 + k];
        else if (k == 48) v = b1[hid];
        a1f[t] = (unsigned short)f2bf(v);
    }
    if (t < 2048) {
        int j = t & 7, lane = (t >> 3) & 63, ks = t >> 9;
        b2f[t] = (unsigned short)f2bf(w2[(lane & 15) * HN + 32 * ks + 8 * (lane >> 4) + j]);
    }
}

// ---------------- Kernel A: perception + MFMA MLP + update ----------------
// 128 pixels/block (4x32), 256 threads = 4 waves. Wave w owns pixels 32w..32w+31.
// R1-verified structure (243 us). LDS = 16384 (union) + 16384 (ybuf) + 8192 (xcT)
// = 40960 B -> 4 blocks/CU. Grid 8x64x32 = 16384 blocks IS the L2 blocking scheme
// (R3 lesson). launch_bounds(256,4): VGPR 64; NEVER 5 (R4: forced 48 -> scratch spills).
__global__ __launch_bounds__(256, 4) void nca_mfma(
    const float* __restrict__ x, const float* __restrict__ upd,
    const unsigned short* __restrict__ a1f, const unsigned short* __restrict__ b2f,
    float* __restrict__ out, float* __restrict__ xn3, unsigned char* __restrict__ bm)
{
    __shared__ __align__(16) union {
        float sx[6][16][40];               // 15360 B (staging; cols j0-4..j0+35)
        unsigned short hb[4][16][128];     // 16384 B (per-wave h scratch, swizzled)
    } u;
    __shared__ __align__(16) unsigned short ybuf[128][64];   // 16384 B (swizzled, pitch 128B)
    __shared__ __align__(16) float xcT[16][128];             //  8192 B (x centers, XOR-swizzled)

    const int b   = blockIdx.z;
    const int i0  = blockIdx.y * 4;
    const int j0  = blockIdx.x * 32;
    const int tid = threadIdx.x;
    const int lane = tid & 63, w = tid >> 6;
    const int l15 = lane & 15, q = lane >> 4;
    const float* xb = x + (size_t)b * CN * HW;
    const float* ub = upd + (size_t)b * HW;

    // ---- weight fragment loads (L1/L2-hot; compiler sinks to use site) ----
    short8 a1[8][2];
#pragma unroll
    for (int mi = 0; mi < 8; ++mi)
#pragma unroll
        for (int ks = 0; ks < 2; ++ks)
            a1[mi][ks] = *(const short8*)(a1f + ((mi * 2 + ks) * 64 + lane) * 8);
    short8 b2[4];
#pragma unroll
    for (int ks = 0; ks < 4; ++ks)
        b2[ks] = *(const short8*)(b2f + (ks * 64 + lane) * 8);

    // ---- stage x tile (+1 halo) into sx[row][ch][col], col = global_j - (j0-4) ----
    const bool interior = (blockIdx.y > 0) & (blockIdx.y < 63) & (blockIdx.x > 0) & (blockIdx.x < 7);
    if (interior) {
        // 960 float4 slots: slot = rc*10 + c4; rc = row*16+ch (96), c4 = 0..9.
        // cols j0-4 .. j0+35, 16B-aligned (j0 % 32 == 0). 4 loads/thread (3 if tid>=192).
        const float* srcb = xb + (size_t)(i0 - 1) * IMW + (j0 - 4);
#pragma unroll
        for (int k = 0; k < 4; ++k) {
            if (k < 3 || tid < 192) {
                const int s  = tid + 256 * k;
                const int rc = s / 10, c4 = s - rc * 10;
                const int rr = rc >> 4, c = rc & 15;
                float4v vv = *(const float4v*)(srcb + (size_t)c * HW + rr * IMW + 4 * c4);
                *(float4v*)&u.sx[rr][c][4 * c4] = vv;
            }
        }
    } else {
        // boundary: scalar with bounds check; cover lds cols 3..36 (global j0-1..j0+32)
#pragma unroll
        for (int k = 0; k < 13; ++k) {
            const int e = tid + 256 * k;
            if (e < 3264) {
                const int rc = e / 34, c34 = e - rc * 34;
                const int rr = rc >> 4, c = rc & 15;
                const int gi = i0 + rr - 1, gj = j0 + c34 - 1;
                float v = 0.f;
                if ((unsigned)gi < IMH && (unsigned)gj < IMW) v = xb[c * HW + gi * IMW + gj];
                u.sx[rr][c][c34 + 3] = v;
            }
        }
    }
    __syncthreads();

    // ---- preload upd (HBM-cold): latency hides under perception + pack + GEMM1 ----
    float4v u4h[2];
#pragma unroll
    for (int half = 0; half < 2; ++half) {
        const int nt = 2 * w + half;
        u4h[half] = *(const float4v*)(ub + (i0 + (nt >> 1)) * IMW + j0
                                      + ((nt & 1) << 4) + (q << 2));
    }

    // ---- perception: thread = (pixel, 8-channel half); pixel tx -> lds col tx+4 ----
    const int pix = tid & 127;
    const int ty  = pix >> 5, tx = pix & 31;
    const int cb  = (tid >> 7) << 3;       // 0 or 8 (wave-uniform)
    float v[24];
#pragma unroll
    for (int c8 = 0; c8 < 8; ++c8) {
        const int c = cb + c8;
        float a00 = u.sx[ty][c][tx + 3],     a01 = u.sx[ty][c][tx + 4],     a02 = u.sx[ty][c][tx + 5];
        float a10 = u.sx[ty + 1][c][tx + 3], a11 = u.sx[ty + 1][c][tx + 4], a12 = u.sx[ty + 1][c][tx + 5];
        float a20 = u.sx[ty + 2][c][tx + 3], a21 = u.sx[ty + 2][c][tx + 4], a22 = u.sx[ty + 2][c][tx + 5];
        v[3 * c8]     = a11;
        v[3 * c8 + 1] = ((a02 - a00) + 2.f * (a12 - a10) + (a22 - a20)) * 0.125f;
        v[3 * c8 + 2] = ((a20 - a00) + 2.f * (a21 - a01) + (a22 - a02)) * 0.125f;
        xcT[c][pix ^ ((c & 7) << 2)] = a11;     // XOR-swizzled (bits 2..4)
        if (cb == 0 && c8 == 3) {
            // begin-alive: maxpool3 of x ch3 (zero-pad == -inf pad since x >= 0)
            float m0 = fmaxf(fmaxf(fmaxf(a00, a01), fmaxf(a02, a10)),
                             fmaxf(fmaxf(a11, a12), fmaxf(fmaxf(a20, a21), a22)));
            bm[(size_t)b * HW + (i0 + ty) * IMW + (j0 + tx)] = (m0 > 0.1f) ? 1 : 0;
        }
    }
    {
        // pack 24 bf16 -> 3 swizzled 16B groups; cb==8 also writes pad groups 6,7
        unsigned int* yrow = (unsigned int*)&ybuf[pix][0];
        const int gbase = (cb >> 3) * 3;
        const int sw = pix & 7;
#pragma unroll
        for (int t = 0; t < 3; ++t) {
            uint4v g;
#pragma unroll
            for (int k = 0; k < 4; ++k) g[k] = pack2(v[8 * t + 2 * k], v[8 * t + 2 * k + 1]);
            *(uint4v*)&yrow[((gbase + t) ^ sw) << 2] = g;
        }
        if (cb == 8) {
            uint4v g6 = {0x3F80u, 0u, 0u, 0u};   // y[48] = 1.0 (bias column)
            uint4v g7 = {};
            *(uint4v*)&yrow[(6 ^ sw) << 2] = g6;
            *(uint4v*)&yrow[(7 ^ sw) << 2] = g7;
        }
    }
    __syncthreads();

    // ---- per wave: GEMM1-T (all 128 hid x 16 pix) -> h scratch -> GEMM2 -> epilogue ----
    float* ob = out + (size_t)b * CN * HW;
    float* n3 = xn3 + (size_t)b * HW;
#pragma unroll
    for (int half = 0; half < 2; ++half) {
        const int nt  = 2 * w + half;
        const int row = 16 * nt + l15;
        const unsigned short* yr = &ybuf[row][0];
        const int rsw = row & 7;
        short8 y0 = *(const short8*)(yr + ((q ^ rsw) << 3));
        short8 y1 = *(const short8*)(yr + (((4 + q) ^ rsw) << 3));
        const int hsw = l15 & 7;
#pragma unroll
        for (int mi = 0; mi < 8; ++mi) {
            float4v acc = {};
            acc = __builtin_amdgcn_mfma_f32_16x16x32_bf16(a1[mi][0], y0, acc, 0, 0, 0);
            acc = __builtin_amdgcn_mfma_f32_16x16x32_bf16(a1[mi][1], y1, acc, 0, 0, 0);
            uint2v hp;
            hp[0] = pack2(fmaxf(acc[0], 0.f), fmaxf(acc[1], 0.f));
            hp[1] = pack2(fmaxf(acc[2], 0.f), fmaxf(acc[3], 0.f));
            // logical col 16mi+4q -> group 2mi+(q>>1), offset 4(q&1); XOR-swizzled
            *(uint2v*)&u.hb[w][l15][(((2 * mi + (q >> 1)) ^ hsw) << 3) + ((q & 1) << 2)] = hp;
        }
        float4v acc2 = {};
#pragma unroll
        for (int ks = 0; ks < 4; ++ks) {
            short8 hf = *(const short8*)&u.hb[w][l15][((4 * ks + q) ^ hsw) << 3];
            acc2 = __builtin_amdgcn_mfma_f32_16x16x32_bf16(hf, b2[ks], acc2, 0, 0, 0);
        }
        // epilogue: pixel p2 = 16nt+4q+r, channel = l15; 4 consecutive pixels -> dwordx4
        const int i  = i0 + (nt >> 1);
        const int jb = j0 + ((nt & 1) << 4) + (q << 2);
        float4v xc4 = *(const float4v*)&xcT[l15][(16 * nt + 4 * q) ^ ((l15 & 7) << 2)];
        float4v o;
#pragma unroll
        for (int r = 0; r < 4; ++r)
            o[r] = fmaf(acc2[r], (u4h[half][r] <= 0.5f) ? 1.f : 0.f, xc4[r]);
        *(float4v*)(ob + l15 * HW + i * IMW + jb) = o;
        if (l15 == 3) *(float4v*)(n3 + i * IMW + jb) = o;
    }
}

// ---------------- Pass 2: alive masking ----------------
// alive = bm & (maxpool3(xn3) > 0.1); zero dead pixels (own pixel only).
// Full-row tiles (8x256), float4-staged.
__global__ __launch_bounds__(256) void nca_pass2(
    const float* __restrict__ xn3, const unsigned char* __restrict__ bm,
    float* __restrict__ out)
{
    __shared__ float s[10][264];           // data at col idx 4..259; halos at 3 and 260
    const int b   = blockIdx.z;
    const int i0  = blockIdx.y * 8;
    const int tid = threadIdx.x;
    const float* n3 = xn3 + (size_t)b * HW;

#pragma unroll
    for (int t = 0; t < 3; ++t) {
        const int idx = tid + 256 * t;     // 640 float4 slots: 10 rows x 64
        if (idx < 640) {
            const int r = idx >> 6, c4 = idx & 63;
            const int gi = i0 + r - 1;
            float4v vv;
            if ((unsigned)gi < IMH) vv = *(const float4v*)(n3 + gi * IMW + 4 * c4);
            else { vv[0] = vv[1] = vv[2] = vv[3] = -1e30f; }
            *(float4v*)&s[r][4 + 4 * c4] = vv;
        }
    }
    if (tid < 20) { const int r = tid >> 1; s[r][(tid & 1) ? 260 : 3] = -1e30f; }
    __syncthreads();

    const int c = tid;                     // column 0..255
    const unsigned char* bmb = bm + (size_t)b * HW + i0 * IMW + c;
    float* ob = out + (size_t)b * CN * HW;
#pragma unroll
    for (int r = 0; r < 8; ++r) {
        float m = fmaxf(fmaxf(fmaxf(s[r][c + 3], s[r][c + 4]), fmaxf(s[r][c + 5], s[r + 1][c + 3])),
                        fmaxf(fmaxf(s[r + 1][c + 4], s[r + 1][c + 5]),
                              fmaxf(fmaxf(s[r + 2][c + 3], s[r + 2][c + 4]), s[r + 2][c + 5])));
        if (!((m > 0.1f) && bmb[r * IMW])) {
            const int i = i0 + r;
#pragma unroll
            for (int ch = 0; ch < CN; ++ch)
                ob[ch * HW + i * IMW + c] = 0.f;
        }
    }
}

extern "C" void kernel_launch(void* const* d_in, const int* in_sizes, int n_in,
                              void* d_out, int out_size, void* d_ws, size_t ws_size,
                              hipStream_t stream) {
    const float* x   = (const float*)d_in[0];
    const float* upd = (const float*)d_in[1];
    const float* w1  = (const float*)d_in[2];
    const float* b1  = (const float*)d_in[3];
    const float* w2  = (const float*)d_in[4];
    float* out = (float*)d_out;

    char* ws = (char*)d_ws;
    float* xn3          = (float*)ws;                            // 8 MiB
    unsigned char* bmp  = (unsigned char*)(ws + (8u << 20));     // 2 MiB
    unsigned short* a1f = (unsigned short*)(ws + (10u << 20));   // 16 KiB
    unsigned short* b2f = a1f + 8192;                            // 4 KiB

    nca_prep<<<32, 256, 0, stream>>>(w1, b1, w2, a1f, b2f);
    nca_mfma<<<dim3(8, 64, 32), 256, 0, stream>>>(x, upd, a1f, b2f, out, xn3, bmp);
    nca_pass2<<<dim3(1, 32, 32), 256, 0, stream>>>(xn3, bmp, out);
}

// Round 6
// 421.574 us; speedup vs baseline: 1.6722x; 1.0774x over previous
//
#include <hip/hip_runtime.h>

#define CN 16
#define HN 128
#define IMH 256
#define IMW 256
#define HW (IMH * IMW)

typedef __attribute__((ext_vector_type(8))) short short8;
typedef __attribute__((ext_vector_type(4))) float float4v;
typedef __attribute__((ext_vector_type(2))) unsigned int uint2v;
typedef __attribute__((ext_vector_type(4))) unsigned int uint4v;

__device__ __forceinline__ unsigned int f2bf(float f) {
    unsigned int u = __builtin_bit_cast(unsigned int, f);
    u += 0x7FFFu + ((u >> 16) & 1u);          // round-to-nearest-even
    return u >> 16;
}
// HW packed f32->bf16 (RNE, identical rounding to f2bf): 1 VALU op instead of ~10
__device__ __forceinline__ unsigned int pack2(float a, float b) {
    unsigned int r;
    asm("v_cvt_pk_bf16_f32 %0, %1, %2" : "=v"(r) : "v"(a), "v"(b));
    return r;
}

// ---------------- Weight prep: fragment-ordered bf16 weights ----------------
__global__ void nca_prep(const float* __restrict__ w1, const float* __restrict__ b1,
                         const float* __restrict__ w2,
                         unsigned short* __restrict__ a1f, unsigned short* __restrict__ b2f)
{
    int t = blockIdx.x * 256 + threadIdx.x;
    if (t < 8192) {
        int j = t & 7, lane = (t >> 3) & 63, ks = (t >> 9) & 1, mi = t >> 10;
        int hid = 16 * mi + (lane & 15);
        int k = 32 * ks + 8 * (lane >> 4) + j;
        float v = 0.f;
        if (k < 48) v = w1[hid * 48 + k];
        else if (k == 48) v = b1[hid];
        a1f[t] = (unsigned short)f2bf(v);
    }
    if (t < 2048) {
        int j = t & 7, lane = (t >> 3) & 63, ks = t >> 9;
        b2f[t] = (unsigned short)f2bf(w2[(lane & 15) * HN + 32 * ks + 8 * (lane >> 4) + j]);
    }
}

// ---------------- Kernel A: perception + MFMA MLP + update ----------------
// 128 pixels/block (4x32), 256 threads = 4 waves. Wave w owns pixels 32w..32w+31.
// R1-verified structure. LDS = 16384 (sx/hb union) + 12288 (ybuf, K=48 only)
// = 28672 B -> 5 blocks/CU with 17 KiB slack. Grid 8x64x32 = 16384 blocks IS the
// L2 blocking scheme (R3 lesson). launch_bounds stays (256,4): VGPR 64 — the
// (256,5) hint forced VGPR 48 and spilled (R4); hoisting loads across perception
// spills too (R5). Nothing extra may live across the perception phase.
__global__ __launch_bounds__(256, 4) void nca_mfma(
    const float* __restrict__ x, const float* __restrict__ upd,
    const unsigned short* __restrict__ a1f, const unsigned short* __restrict__ b2f,
    float* __restrict__ out, float* __restrict__ xn3, unsigned char* __restrict__ bm)
{
    __shared__ __align__(16) union {
        float sx[6][16][34];               // 13056 B (staging; dead after perception)
        unsigned short hb[4][16][128];     // 16384 B (per-wave h scratch, swizzled)
    } u;
    __shared__ __align__(16) unsigned short ybuf[128][48];   // 12288 B (K=0..47; bias/pad synthesized)

    const int b   = blockIdx.z;
    const int i0  = blockIdx.y * 4;
    const int j0  = blockIdx.x * 32;
    const int tid = threadIdx.x;
    const int lane = tid & 63, w = tid >> 6;
    const int l15 = lane & 15, q = lane >> 4;
    const float* xb = x + (size_t)b * CN * HW;

    // ---- weight fragment loads (L1/L2-hot; compiler sinks to use site) ----
    short8 a1[8][2];
#pragma unroll
    for (int mi = 0; mi < 8; ++mi)
#pragma unroll
        for (int ks = 0; ks < 2; ++ks)
            a1[mi][ks] = *(const short8*)(a1f + ((mi * 2 + ks) * 64 + lane) * 8);
    short8 b2[4];
#pragma unroll
    for (int ks = 0; ks < 4; ++ks)
        b2[ks] = *(const short8*)(b2f + (ks * 64 + lane) * 8);

    // ---- stage x tile (+1 halo): layout sx[row 0..5][ch][col 0..33] (R1 verbatim) ----
    const bool interior = (blockIdx.y > 0) & (blockIdx.y < 63) & (blockIdx.x > 0) & (blockIdx.x < 7);
    {
        const int col = tid & 31;
        if (interior) {
            const float* src = xb + (i0 - 1) * IMW + (j0 - 1);
#pragma unroll
            for (int rt = tid >> 5; rt < 96; rt += 8)
                u.sx[rt >> 4][rt & 15][col] = src[(rt & 15) * HW + (rt >> 4) * IMW + col];
            if (tid < 192) {
                int rt = tid >> 1, col2 = 32 + (tid & 1);
                u.sx[rt >> 4][rt & 15][col2] = src[(rt & 15) * HW + (rt >> 4) * IMW + col2];
            }
        } else {
#pragma unroll
            for (int rt = tid >> 5; rt < 96; rt += 8) {
                int rr = rt >> 4, c = rt & 15;
                int gi = i0 + rr - 1, gj = j0 + col - 1;
                float v = 0.f;
                if ((unsigned)gi < IMH && (unsigned)gj < IMW) v = xb[c * HW + gi * IMW + gj];
                u.sx[rr][c][col] = v;
            }
            if (tid < 192) {
                int rt = tid >> 1, col2 = 32 + (tid & 1);
                int rr = rt >> 4, c = rt & 15;
                int gi = i0 + rr - 1, gj = j0 + col2 - 1;
                float v = 0.f;
                if ((unsigned)gi < IMH && (unsigned)gj < IMW) v = xb[c * HW + gi * IMW + gj];
                u.sx[rr][c][col2] = v;
            }
        }
    }
    __syncthreads();

    // ---- perception: thread = (pixel, 8-channel half) ----
    const int pix = tid & 127;
    const int ty  = pix >> 5, tx = pix & 31;
    const int cb  = (tid >> 7) << 3;       // 0 or 8 (wave-uniform)
    float v[24];
#pragma unroll
    for (int c8 = 0; c8 < 8; ++c8) {
        const int c = cb + c8;
        float a00 = u.sx[ty][c][tx],     a01 = u.sx[ty][c][tx + 1],     a02 = u.sx[ty][c][tx + 2];
        float a10 = u.sx[ty + 1][c][tx], a11 = u.sx[ty + 1][c][tx + 1], a12 = u.sx[ty + 1][c][tx + 2];
        float a20 = u.sx[ty + 2][c][tx], a21 = u.sx[ty + 2][c][tx + 1], a22 = u.sx[ty + 2][c][tx + 2];
        v[3 * c8]     = a11;
        v[3 * c8 + 1] = ((a02 - a00) + 2.f * (a12 - a10) + (a22 - a20)) * 0.125f;
        v[3 * c8 + 2] = ((a20 - a00) + 2.f * (a21 - a01) + (a22 - a02)) * 0.125f;
        if (cb == 0 && c8 == 3) {
            // begin-alive: maxpool3 of x ch3 (zero-pad == -inf pad since x >= 0)
            float m0 = fmaxf(fmaxf(fmaxf(a00, a01), fmaxf(a02, a10)),
                             fmaxf(fmaxf(a11, a12), fmaxf(fmaxf(a20, a21), a22)));
            bm[(size_t)b * HW + (i0 + ty) * IMW + (j0 + tx)] = (m0 > 0.1f) ? 1 : 0;
        }
    }
    {
        // pack 24 bf16 -> 3 swizzled 16B groups (groups 0..5 total; XOR(pix&1) swizzle).
        // K slots 48..63 (bias + pad) are NOT stored — synthesized at the GEMM1 read.
        unsigned int* yrow = (unsigned int*)&ybuf[pix][0];
        const int gbase = (cb >> 3) * 3;
        const int sw = pix & 1;
#pragma unroll
        for (int t = 0; t < 3; ++t) {
            uint4v g;
#pragma unroll
            for (int k = 0; k < 4; ++k) g[k] = pack2(v[8 * t + 2 * k], v[8 * t + 2 * k + 1]);
            *(uint4v*)&yrow[((gbase + t) ^ sw) << 2] = g;
        }
    }
    __syncthreads();

    // ---- per wave: GEMM1-T (all 128 hid x 16 pix) -> h scratch -> GEMM2 -> epilogue ----
    const float* ub = upd + (size_t)b * HW;
    float* ob = out + (size_t)b * CN * HW;
    float* n3 = xn3 + (size_t)b * HW;
#pragma unroll
    for (int half = 0; half < 2; ++half) {
        const int nt  = 2 * w + half;
        const int row = 16 * nt + l15;
        const unsigned short* yr = &ybuf[row][0];
        const int rsw = row & 1;
        short8 y0 = *(const short8*)(yr + ((q ^ rsw) << 3));
        // y1: k=32..47 from LDS (q<2); k=48 = bias column 1.0 (q==2, j==0); k>48 = 0
        short8 y1 = {};
        if (q < 2)      y1 = *(const short8*)(yr + (((4 + q) ^ rsw) << 3));
        else if (q == 2) y1[0] = (short)0x3F80;   // bf16(1.0)
        const int hsw = l15 & 7;
#pragma unroll
        for (int mi = 0; mi < 8; ++mi) {
            float4v acc = {};
            acc = __builtin_amdgcn_mfma_f32_16x16x32_bf16(a1[mi][0], y0, acc, 0, 0, 0);
            acc = __builtin_amdgcn_mfma_f32_16x16x32_bf16(a1[mi][1], y1, acc, 0, 0, 0);
            uint2v hp;
            hp[0] = pack2(fmaxf(acc[0], 0.f), fmaxf(acc[1], 0.f));
            hp[1] = pack2(fmaxf(acc[2], 0.f), fmaxf(acc[3], 0.f));
            // logical col 16mi+4q -> group 2mi+(q>>1), offset 4(q&1); XOR-swizzled
            *(uint2v*)&u.hb[w][l15][(((2 * mi + (q >> 1)) ^ hsw) << 3) + ((q & 1) << 2)] = hp;
        }
        float4v acc2 = {};
#pragma unroll
        for (int ks = 0; ks < 4; ++ks) {
            short8 hf = *(const short8*)&u.hb[w][l15][((4 * ks + q) ^ hsw) << 3];
            acc2 = __builtin_amdgcn_mfma_f32_16x16x32_bf16(hf, b2[ks], acc2, 0, 0, 0);
        }
        // epilogue: pixel p2 = 16nt+4q+r, channel = l15; 4 consecutive pixels -> dwordx4.
        // x centers re-read from global (lines staged by this block -> L2-hot);
        // this replaced the 8 KiB xcT LDS buffer (part of the 5-blocks/CU unlock).
        const int i  = i0 + (nt >> 1);
        const int jb = j0 + ((nt & 1) << 4) + (q << 2);
        float4v xc4 = *(const float4v*)(xb + (size_t)l15 * HW + i * IMW + jb);
        float4v u4  = *(const float4v*)(ub + i * IMW + jb);
        float4v o;
#pragma unroll
        for (int r = 0; r < 4; ++r)
            o[r] = fmaf(acc2[r], (u4[r] <= 0.5f) ? 1.f : 0.f, xc4[r]);
        *(float4v*)(ob + l15 * HW + i * IMW + jb) = o;
        if (l15 == 3) *(float4v*)(n3 + i * IMW + jb) = o;
    }
}

// ---------------- Pass 2: alive masking ----------------
// alive = bm & (maxpool3(xn3) > 0.1); zero dead pixels (own pixel only).
// Full-row tiles (8x256), float4-staged.
__global__ __launch_bounds__(256) void nca_pass2(
    const float* __restrict__ xn3, const unsigned char* __restrict__ bm,
    float* __restrict__ out)
{
    __shared__ float s[10][264];           // data at col idx 4..259; halos at 3 and 260
    const int b   = blockIdx.z;
    const int i0  = blockIdx.y * 8;
    const int tid = threadIdx.x;
    const float* n3 = xn3 + (size_t)b * HW;

#pragma unroll
    for (int t = 0; t < 3; ++t) {
        const int idx = tid + 256 * t;     // 640 float4 slots: 10 rows x 64
        if (idx < 640) {
            const int r = idx >> 6, c4 = idx & 63;
            const int gi = i0 + r - 1;
            float4v vv;
            if ((unsigned)gi < IMH) vv = *(const float4v*)(n3 + gi * IMW + 4 * c4);
            else { vv[0] = vv[1] = vv[2] = vv[3] = -1e30f; }
            *(float4v*)&s[r][4 + 4 * c4] = vv;
        }
    }
    if (tid < 20) { const int r = tid >> 1; s[r][(tid & 1) ? 260 : 3] = -1e30f; }
    __syncthreads();

    const int c = tid;                     // column 0..255
    const unsigned char* bmb = bm + (size_t)b * HW + i0 * IMW + c;
    float* ob = out + (size_t)b * CN * HW;
#pragma unroll
    for (int r = 0; r < 8; ++r) {
        float m = fmaxf(fmaxf(fmaxf(s[r][c + 3], s[r][c + 4]), fmaxf(s[r][c + 5], s[r + 1][c + 3])),
                        fmaxf(fmaxf(s[r + 1][c + 4], s[r + 1][c + 5]),
                              fmaxf(fmaxf(s[r + 2][c + 3], s[r + 2][c + 4]), s[r + 2][c + 5])));
        if (!((m > 0.1f) && bmb[r * IMW])) {
            const int i = i0 + r;
#pragma unroll
            for (int ch = 0; ch < CN; ++ch)
                ob[ch * HW + i * IMW + c] = 0.f;
        }
    }
}

extern "C" void kernel_launch(void* const* d_in, const int* in_sizes, int n_in,
                              void* d_out, int out_size, void* d_ws, size_t ws_size,
                              hipStream_t stream) {
    const float* x   = (const float*)d_in[0];
    const float* upd = (const float*)d_in[1];
    const float* w1  = (const float*)d_in[2];
    const float* b1  = (const float*)d_in[3];
    const float* w2  = (const float*)d_in[4];
    float* out = (float*)d_out;

    char* ws = (char*)d_ws;
    float* xn3          = (float*)ws;                            // 8 MiB
    unsigned char* bmp  = (unsigned char*)(ws + (8u << 20));     // 2 MiB
    unsigned short* a1f = (unsigned short*)(ws + (10u << 20));   // 16 KiB
    unsigned short* b2f = a1f + 8192;                            // 4 KiB

    nca_prep<<<32, 256, 0, stream>>>(w1, b1, w2, a1f, b2f);
    nca_mfma<<<dim3(8, 64, 32), 256, 0, stream>>>(x, upd, a1f, b2f, out, xn3, bmp);
    nca_pass2<<<dim3(1, 32, 32), 256, 0, stream>>>(xn3, bmp, out);
}

// Round 7
// 418.925 us; speedup vs baseline: 1.6828x; 1.0063x over previous
//
#include <hip/hip_runtime.h>

#define CN 16
#define HN 128
#define IMH 256
#define IMW 256
#define HW (IMH * IMW)

typedef __attribute__((ext_vector_type(8))) short short8;
typedef __attribute__((ext_vector_type(4))) float float4v;
typedef __attribute__((ext_vector_type(2))) unsigned int uint2v;
typedef __attribute__((ext_vector_type(4))) unsigned int uint4v;

__device__ __forceinline__ unsigned int f2bf(float f) {
    unsigned int u = __builtin_bit_cast(unsigned int, f);
    u += 0x7FFFu + ((u >> 16) & 1u);          // round-to-nearest-even
    return u >> 16;
}
// HW packed f32->bf16 (RNE, identical rounding to f2bf): 1 VALU op instead of ~10
__device__ __forceinline__ unsigned int pack2(float a, float b) {
    unsigned int r;
    asm("v_cvt_pk_bf16_f32 %0, %1, %2" : "=v"(r) : "v"(a), "v"(b));
    return r;
}

// ---------------- Weight prep: fragment-ordered bf16 weights ----------------
__global__ void nca_prep(const float* __restrict__ w1, const float* __restrict__ b1,
                         const float* __restrict__ w2,
                         unsigned short* __restrict__ a1f, unsigned short* __restrict__ b2f)
{
    int t = blockIdx.x * 256 + threadIdx.x;
    if (t < 8192) {
        int j = t & 7, lane = (t >> 3) & 63, ks = (t >> 9) & 1, mi = t >> 10;
        int hid = 16 * mi + (lane & 15);
        int k = 32 * ks + 8 * (lane >> 4) + j;
        float v = 0.f;
        if (k < 48) v = w1[hid * 48 + k];
        else if (k == 48) v = b1[hid];
        a1f[t] = (unsigned short)f2bf(v);
    }
    if (t < 2048) {
        int j = t & 7, lane = (t >> 3) & 63, ks = t >> 9;
        b2f[t] = (unsigned short)f2bf(w2[(lane & 15) * HN + 32 * ks + 8 * (lane >> 4) + j]);
    }
}

// ---------------- Kernel A: perception + MFMA MLP + update ----------------
// 128 pixels/block (4x32), 256 threads = 4 waves. Wave w owns pixels 32w..32w+31.
// LDS = 16384 (sx/hb union) + 16384 (ybuf) + 512 (ubuf) = 33280 B -> 4 blocks/CU.
// Session rules: grid 8x64x32 = 16384 blocks IS the L2 blocking scheme (R3: coarser
// tiles -> 6x HBM over-fetch). launch_bounds stays (256,4) — (256,5) forces VGPR 48
// and spills (R4). Nothing extra may live in VGPRs across perception (R5 spill).
// Wave-slot occupancy is NOT the limiter (R6: LDS 28672 -> occupancy unchanged).
// upd is staged through LDS: its HBM latency merges with the x-stage vmcnt wait,
// removing the 2x ~900cy cold-load stall the epilogue used to expose.
__global__ __launch_bounds__(256, 4) void nca_mfma(
    const float* __restrict__ x, const float* __restrict__ upd,
    const unsigned short* __restrict__ a1f, const unsigned short* __restrict__ b2f,
    float* __restrict__ out, float* __restrict__ xn3, unsigned char* __restrict__ bm)
{
    __shared__ __align__(16) union {
        float sx[6][16][34];               // 13056 B (staging; dead after perception)
        unsigned short hb[4][16][128];     // 16384 B (per-wave h scratch, swizzled)
    } u;
    __shared__ __align__(16) unsigned short ybuf[128][64];   // 16384 B (swizzled, pitch 128B)
    __shared__ __align__(16) float ubuf[128];                //   512 B (upd tile, pixel-linear)

    const int b   = blockIdx.z;
    const int i0  = blockIdx.y * 4;
    const int j0  = blockIdx.x * 32;
    const int tid = threadIdx.x;
    const int lane = tid & 63, w = tid >> 6;
    const int l15 = lane & 15, q = lane >> 4;
    const float* xb = x + (size_t)b * CN * HW;
    const float* ub = upd + (size_t)b * HW;

    // ---- weight fragment loads (L1/L2-hot; compiler sinks to use site) ----
    short8 a1[8][2];
#pragma unroll
    for (int mi = 0; mi < 8; ++mi)
#pragma unroll
        for (int ks = 0; ks < 2; ++ks)
            a1[mi][ks] = *(const short8*)(a1f + ((mi * 2 + ks) * 64 + lane) * 8);
    short8 b2[4];
#pragma unroll
    for (int ks = 0; ks < 4; ++ks)
        b2[ks] = *(const short8*)(b2f + (ks * 64 + lane) * 8);

    // ---- stage x tile (+1 halo) + upd tile; all loads drain at barrier (a) ----
    const bool interior = (blockIdx.y > 0) & (blockIdx.y < 63) & (blockIdx.x > 0) & (blockIdx.x < 7);
    {
        const int col = tid & 31;
        if (interior) {
            const float* src = xb + (i0 - 1) * IMW + (j0 - 1);
#pragma unroll
            for (int rt = tid >> 5; rt < 96; rt += 8)
                u.sx[rt >> 4][rt & 15][col] = src[(rt & 15) * HW + (rt >> 4) * IMW + col];
            if (tid < 192) {
                int rt = tid >> 1, col2 = 32 + (tid & 1);
                u.sx[rt >> 4][rt & 15][col2] = src[(rt & 15) * HW + (rt >> 4) * IMW + col2];
            }
        } else {
#pragma unroll
            for (int rt = tid >> 5; rt < 96; rt += 8) {
                int rr = rt >> 4, c = rt & 15;
                int gi = i0 + rr - 1, gj = j0 + col - 1;
                float v = 0.f;
                if ((unsigned)gi < IMH && (unsigned)gj < IMW) v = xb[c * HW + gi * IMW + gj];
                u.sx[rr][c][col] = v;
            }
            if (tid < 192) {
                int rt = tid >> 1, col2 = 32 + (tid & 1);
                int rr = rt >> 4, c = rt & 15;
                int gi = i0 + rr - 1, gj = j0 + col2 - 1;
                float v = 0.f;
                if ((unsigned)gi < IMH && (unsigned)gj < IMW) v = xb[c * HW + gi * IMW + gj];
                u.sx[rr][c][col2] = v;
            }
        }
        // upd tile (128 floats, pixel-linear): latency merges with the x-stage wait
        if (tid < 128) ubuf[tid] = ub[(i0 + (tid >> 5)) * IMW + j0 + (tid & 31)];
    }
    __syncthreads();

    // ---- perception: thread = (pixel, 8-channel half) ----
    const int pix = tid & 127;
    const int ty  = pix >> 5, tx = pix & 31;
    const int cb  = (tid >> 7) << 3;       // 0 or 8 (wave-uniform)
    float v[24];
#pragma unroll
    for (int c8 = 0; c8 < 8; ++c8) {
        const int c = cb + c8;
        float a00 = u.sx[ty][c][tx],     a01 = u.sx[ty][c][tx + 1],     a02 = u.sx[ty][c][tx + 2];
        float a10 = u.sx[ty + 1][c][tx], a11 = u.sx[ty + 1][c][tx + 1], a12 = u.sx[ty + 1][c][tx + 2];
        float a20 = u.sx[ty + 2][c][tx], a21 = u.sx[ty + 2][c][tx + 1], a22 = u.sx[ty + 2][c][tx + 2];
        v[3 * c8]     = a11;
        v[3 * c8 + 1] = ((a02 - a00) + 2.f * (a12 - a10) + (a22 - a20)) * 0.125f;
        v[3 * c8 + 2] = ((a20 - a00) + 2.f * (a21 - a01) + (a22 - a02)) * 0.125f;
        if (cb == 0 && c8 == 3) {
            // begin-alive: maxpool3 of x ch3 (zero-pad == -inf pad since x >= 0)
            float m0 = fmaxf(fmaxf(fmaxf(a00, a01), fmaxf(a02, a10)),
                             fmaxf(fmaxf(a11, a12), fmaxf(fmaxf(a20, a21), a22)));
            bm[(size_t)b * HW + (i0 + ty) * IMW + (j0 + tx)] = (m0 > 0.1f) ? 1 : 0;
        }
    }
    {
        // pack 24 bf16 -> 3 swizzled 16B groups; cb==8 also writes pad groups 6,7
        unsigned int* yrow = (unsigned int*)&ybuf[pix][0];
        const int gbase = (cb >> 3) * 3;
        const int sw = pix & 7;
#pragma unroll
        for (int t = 0; t < 3; ++t) {
            uint4v g;
#pragma unroll
            for (int k = 0; k < 4; ++k) g[k] = pack2(v[8 * t + 2 * k], v[8 * t + 2 * k + 1]);
            *(uint4v*)&yrow[((gbase + t) ^ sw) << 2] = g;
        }
        if (cb == 8) {
            uint4v g6 = {0x3F80u, 0u, 0u, 0u};   // y[48] = 1.0 (bias column)
            uint4v g7 = {};
            *(uint4v*)&yrow[(6 ^ sw) << 2] = g6;
            *(uint4v*)&yrow[(7 ^ sw) << 2] = g7;
        }
    }
    __syncthreads();

    // ---- per wave: GEMM1-T (all 128 hid x 16 pix) -> h scratch -> GEMM2 -> epilogue ----
    float* ob = out + (size_t)b * CN * HW;
    float* n3 = xn3 + (size_t)b * HW;
#pragma unroll
    for (int half = 0; half < 2; ++half) {
        const int nt  = 2 * w + half;
        const int row = 16 * nt + l15;
        const unsigned short* yr = &ybuf[row][0];
        const int rsw = row & 7;
        short8 y0 = *(const short8*)(yr + ((q ^ rsw) << 3));
        short8 y1 = *(const short8*)(yr + (((4 + q) ^ rsw) << 3));
        const int hsw = l15 & 7;
#pragma unroll
        for (int mi = 0; mi < 8; ++mi) {
            float4v acc = {};
            acc = __builtin_amdgcn_mfma_f32_16x16x32_bf16(a1[mi][0], y0, acc, 0, 0, 0);
            acc = __builtin_amdgcn_mfma_f32_16x16x32_bf16(a1[mi][1], y1, acc, 0, 0, 0);
            uint2v hp;
            hp[0] = pack2(fmaxf(acc[0], 0.f), fmaxf(acc[1], 0.f));
            hp[1] = pack2(fmaxf(acc[2], 0.f), fmaxf(acc[3], 0.f));
            // logical col 16mi+4q -> group 2mi+(q>>1), offset 4(q&1); XOR-swizzled
            *(uint2v*)&u.hb[w][l15][(((2 * mi + (q >> 1)) ^ hsw) << 3) + ((q & 1) << 2)] = hp;
        }
        float4v acc2 = {};
#pragma unroll
        for (int ks = 0; ks < 4; ++ks) {
            short8 hf = *(const short8*)&u.hb[w][l15][((4 * ks + q) ^ hsw) << 3];
            acc2 = __builtin_amdgcn_mfma_f32_16x16x32_bf16(hf, b2[ks], acc2, 0, 0, 0);
        }
        // epilogue: pixel p2 = 16nt+4q+r, channel = l15; 4 consecutive pixels -> dwordx4.
        // upd from LDS (staged; broadcast read); x centers from global (L2-hot, R6-proven).
        const int i  = i0 + (nt >> 1);
        const int jb = j0 + ((nt & 1) << 4) + (q << 2);
        float4v xc4 = *(const float4v*)(xb + (size_t)l15 * HW + i * IMW + jb);
        float4v u4  = *(const float4v*)&ubuf[16 * nt + (q << 2)];
        float4v o;
#pragma unroll
        for (int r = 0; r < 4; ++r)
            o[r] = fmaf(acc2[r], (u4[r] <= 0.5f) ? 1.f : 0.f, xc4[r]);
        *(float4v*)(ob + l15 * HW + i * IMW + jb) = o;
        if (l15 == 3) *(float4v*)(n3 + i * IMW + jb) = o;
    }
}

// ---------------- Pass 2: alive masking ----------------
// alive = bm & (maxpool3(xn3) > 0.1); zero dead pixels (own pixel only).
// Full-row tiles (8x256), float4-staged.
__global__ __launch_bounds__(256) void nca_pass2(
    const float* __restrict__ xn3, const unsigned char* __restrict__ bm,
    float* __restrict__ out)
{
    __shared__ float s[10][264];           // data at col idx 4..259; halos at 3 and 260
    const int b   = blockIdx.z;
    const int i0  = blockIdx.y * 8;
    const int tid = threadIdx.x;
    const float* n3 = xn3 + (size_t)b * HW;

#pragma unroll
    for (int t = 0; t < 3; ++t) {
        const int idx = tid + 256 * t;     // 640 float4 slots: 10 rows x 64
        if (idx < 640) {
            const int r = idx >> 6, c4 = idx & 63;
            const int gi = i0 + r - 1;
            float4v vv;
            if ((unsigned)gi < IMH) vv = *(const float4v*)(n3 + gi * IMW + 4 * c4);
            else { vv[0] = vv[1] = vv[2] = vv[3] = -1e30f; }
            *(float4v*)&s[r][4 + 4 * c4] = vv;
        }
    }
    if (tid < 20) { const int r = tid >> 1; s[r][(tid & 1) ? 260 : 3] = -1e30f; }
    __syncthreads();

    const int c = tid;                     // column 0..255
    const unsigned char* bmb = bm + (size_t)b * HW + i0 * IMW + c;
    float* ob = out + (size_t)b * CN * HW;
#pragma unroll
    for (int r = 0; r < 8; ++r) {
        float m = fmaxf(fmaxf(fmaxf(s[r][c + 3], s[r][c + 4]), fmaxf(s[r][c + 5], s[r + 1][c + 3])),
                        fmaxf(fmaxf(s[r + 1][c + 4], s[r + 1][c + 5]),
                              fmaxf(fmaxf(s[r + 2][c + 3], s[r + 2][c + 4]), s[r + 2][c + 5])));
        if (!((m > 0.1f) && bmb[r * IMW])) {
            const int i = i0 + r;
#pragma unroll
            for (int ch = 0; ch < CN; ++ch)
                ob[ch * HW + i * IMW + c] = 0.f;
        }
    }
}

extern "C" void kernel_launch(void* const* d_in, const int* in_sizes, int n_in,
                              void* d_out, int out_size, void* d_ws, size_t ws_size,
                              hipStream_t stream) {
    const float* x   = (const float*)d_in[0];
    const float* upd = (const float*)d_in[1];
    const float* w1  = (const float*)d_in[2];
    const float* b1  = (const float*)d_in[3];
    const float* w2  = (const float*)d_in[4];
    float* out = (float*)d_out;

    char* ws = (char*)d_ws;
    float* xn3          = (float*)ws;                            // 8 MiB
    unsigned char* bmp  = (unsigned char*)(ws + (8u << 20));     // 2 MiB
    unsigned short* a1f = (unsigned short*)(ws + (10u << 20));   // 16 KiB
    unsigned short* b2f = a1f + 8192;                            // 4 KiB

    nca_prep<<<32, 256, 0, stream>>>(w1, b1, w2, a1f, b2f);
    nca_mfma<<<dim3(8, 64, 32), 256, 0, stream>>>(x, upd, a1f, b2f, out, xn3, bmp);
    nca_pass2<<<dim3(1, 32, 32), 256, 0, stream>>>(xn3, bmp, out);
}

// Round 8
// 410.395 us; speedup vs baseline: 1.7178x; 1.0208x over previous
//
#include <hip/hip_runtime.h>

#define CN 16
#define HN 128
#define IMH 256
#define IMW 256
#define HW (IMH * IMW)

typedef __attribute__((ext_vector_type(8))) short short8;
typedef __attribute__((ext_vector_type(4))) float float4v;
typedef __attribute__((ext_vector_type(2))) unsigned int uint2v;
typedef __attribute__((ext_vector_type(4))) unsigned int uint4v;

__device__ __forceinline__ unsigned int f2bf(float f) {
    unsigned int u = __builtin_bit_cast(unsigned int, f);
    u += 0x7FFFu + ((u >> 16) & 1u);          // round-to-nearest-even
    return u >> 16;
}
// HW packed f32->bf16 (RNE, identical rounding to f2bf): 1 VALU op instead of ~10
__device__ __forceinline__ unsigned int pack2(float a, float b) {
    unsigned int r;
    asm("v_cvt_pk_bf16_f32 %0, %1, %2" : "=v"(r) : "v"(a), "v"(b));
    return r;
}

// ---------------- Weight prep: fragment-ordered bf16 weights ----------------
// Physical k-slot permutation (must match nca_mfma's ybuf pack):
//   slot s = 32ks + 8q + j; cp = s>>3 = 4ks+q; m = s&7 = j.
//   m<6  -> w1[hid][6*cp + m]   (features of channel pair cp: {cen,sx,sy}x2)
//   s==6 -> b1[hid]             (bias; y slot 6 = 1.0 from the cp==0 pack word)
//   else -> 0                   (slots 8cp+6,7: y is garbage/zero, weight 0)
__global__ void nca_prep(const float* __restrict__ w1, const float* __restrict__ b1,
                         const float* __restrict__ w2,
                         unsigned short* __restrict__ a1f, unsigned short* __restrict__ b2f)
{
    int t = blockIdx.x * 256 + threadIdx.x;
    if (t < 8192) {
        int j = t & 7, lane = (t >> 3) & 63, ks = (t >> 9) & 1, mi = t >> 10;
        int hid = 16 * mi + (lane & 15);
        int cp = 4 * ks + (lane >> 4);
        float v = 0.f;
        if (j < 6) v = w1[hid * 48 + 6 * cp + j];
        else if (cp == 0 && j == 6) v = b1[hid];
        a1f[t] = (unsigned short)f2bf(v);
    }
    if (t < 2048) {
        int j = t & 7, lane = (t >> 3) & 63, ks = t >> 9;
        b2f[t] = (unsigned short)f2bf(w2[(lane & 15) * HN + 32 * ks + 8 * (lane >> 4) + j]);
    }
}

// ---------------- Kernel A: perception + MFMA MLP + update ----------------
// 128 pixels/block (4x32), 256 threads = 4 waves.
// LDS = 16384 (sx/hb union) + 16384 (ybuf) + 8192 (xcT) = 40960 B -> 4 blocks/CU.
// Session rules: grid 8x64x32 IS the L2 blocking scheme (R3). launch_bounds(256,4)
// only — (256,5) forces VGPR 48 + spills (R4). Nothing extra lives in VGPRs across
// perception (R5). Wave-slot occupancy is not the limiter (R6). xcT in LDS beats
// global x re-read by ~9us (R6/R7).
// R8: (1) nt = w + 4*half -> all 4 waves co-write the same rows' adjacent 64B
// halves => full 128B lines merge in L2 (WRITE_SIZE was 1.5x ideal).
// (2) quad-pixel perception: 12x ds_read_b128 per thread instead of 72x b32.
__global__ __launch_bounds__(256, 4) void nca_mfma(
    const float* __restrict__ x, const float* __restrict__ upd,
    const unsigned short* __restrict__ a1f, const unsigned short* __restrict__ b2f,
    float* __restrict__ out, float* __restrict__ xn3, unsigned char* __restrict__ bm)
{
    __shared__ __align__(16) union {
        float sx[6][16][36];               // 13824 B (staging; pitch 36 -> rows 16B-aligned)
        unsigned short hb[4][16][128];     // 16384 B (per-wave h scratch, swizzled)
    } u;
    __shared__ __align__(16) unsigned short ybuf[128][64];   // 16384 B (group-swizzled, pitch 128B)
    __shared__ __align__(16) float xcT[16][128];             //  8192 B (x centers, XOR-swizzled)

    const int b   = blockIdx.z;
    const int i0  = blockIdx.y * 4;
    const int j0  = blockIdx.x * 32;
    const int tid = threadIdx.x;
    const int lane = tid & 63, w = tid >> 6;
    const int l15 = lane & 15, q = lane >> 4;
    const float* xb = x + (size_t)b * CN * HW;
    const float* ub = upd + (size_t)b * HW;

    // ---- weight fragment loads (L1/L2-hot; compiler sinks to use site) ----
    short8 a1[8][2];
#pragma unroll
    for (int mi = 0; mi < 8; ++mi)
#pragma unroll
        for (int ks = 0; ks < 2; ++ks)
            a1[mi][ks] = *(const short8*)(a1f + ((mi * 2 + ks) * 64 + lane) * 8);
    short8 b2[4];
#pragma unroll
    for (int ks = 0; ks < 4; ++ks)
        b2[ks] = *(const short8*)(b2f + (ks * 64 + lane) * 8);

    // ---- stage x tile (+1 halo): sx[row 0..5][ch][col 0..33]; cols 34,35 unused ----
    const bool interior = (blockIdx.y > 0) & (blockIdx.y < 63) & (blockIdx.x > 0) & (blockIdx.x < 7);
    {
        const int col = tid & 31;
        if (interior) {
            const float* src = xb + (i0 - 1) * IMW + (j0 - 1);
#pragma unroll
            for (int rt = tid >> 5; rt < 96; rt += 8)
                u.sx[rt >> 4][rt & 15][col] = src[(rt & 15) * HW + (rt >> 4) * IMW + col];
            if (tid < 192) {
                int rt = tid >> 1, col2 = 32 + (tid & 1);
                u.sx[rt >> 4][rt & 15][col2] = src[(rt & 15) * HW + (rt >> 4) * IMW + col2];
            }
        } else {
#pragma unroll
            for (int rt = tid >> 5; rt < 96; rt += 8) {
                int rr = rt >> 4, c = rt & 15;
                int gi = i0 + rr - 1, gj = j0 + col - 1;
                float v = 0.f;
                if ((unsigned)gi < IMH && (unsigned)gj < IMW) v = xb[c * HW + gi * IMW + gj];
                u.sx[rr][c][col] = v;
            }
            if (tid < 192) {
                int rt = tid >> 1, col2 = 32 + (tid & 1);
                int rr = rt >> 4, c = rt & 15;
                int gi = i0 + rr - 1, gj = j0 + col2 - 1;
                float v = 0.f;
                if ((unsigned)gi < IMH && (unsigned)gj < IMW) v = xb[c * HW + gi * IMW + gj];
                u.sx[rr][c][col2] = v;
            }
        }
    }
    __syncthreads();

    // ---- perception: thread = (pixel-quad qd, channel-pair cp) ----
    // Pixel p = 4*qd + r (r=0..3). sx col for global col j0+t is t+1; quad reads
    // aligned cols tx4..tx4+7 covering pixels tx4-1..tx4+6 -> pixel r uses f[r..r+2].
    const int qd  = tid & 31;
    const int cp  = tid >> 5;              // wave-uniform pairs {2w,2w+1}
    const int ty  = qd >> 3, tx4 = (qd & 7) << 2;

    unsigned int w0p[4], w1p[4], w2p[4];
    float4v cen0v, cen1v;
    {   // channel c0 = 2cp
        const int c = 2 * cp;
        float4v r0a = *(const float4v*)&u.sx[ty][c][tx4];
        float4v r0b = *(const float4v*)&u.sx[ty][c][tx4 + 4];
        float4v r1a = *(const float4v*)&u.sx[ty + 1][c][tx4];
        float4v r1b = *(const float4v*)&u.sx[ty + 1][c][tx4 + 4];
        float4v r2a = *(const float4v*)&u.sx[ty + 2][c][tx4];
        float4v r2b = *(const float4v*)&u.sx[ty + 2][c][tx4 + 4];
        float S[6], D[6];
#pragma unroll
        for (int j = 0; j < 6; ++j) {
            float a0 = (j < 4) ? r0a[j] : r0b[j - 4];
            float a1v = (j < 4) ? r1a[j] : r1b[j - 4];
            float a2 = (j < 4) ? r2a[j] : r2b[j - 4];
            S[j] = fmaf(2.f, a1v, a0) + a2;
            D[j] = a2 - a0;
        }
        float sy0[4];
#pragma unroll
        for (int r = 0; r < 4; ++r) {
            float cen = (r + 1 < 4) ? r1a[r + 1] : r1b[r - 3];
            float sxv = (S[r + 2] - S[r]) * 0.125f;
            sy0[r] = (fmaf(2.f, D[r + 1], D[r]) + D[r + 2]) * 0.125f;
            w0p[r] = pack2(cen, sxv);
            cen0v[r] = cen;
        }
        // stash sy0 into w1p low halves later (needs cen1); hold in w1p temporarily
#pragma unroll
        for (int r = 0; r < 4; ++r) w1p[r] = __builtin_bit_cast(unsigned int, sy0[r]);
    }
    {   // channel c1 = 2cp+1
        const int c = 2 * cp + 1;
        float4v r0a = *(const float4v*)&u.sx[ty][c][tx4];
        float4v r0b = *(const float4v*)&u.sx[ty][c][tx4 + 4];
        float4v r1a = *(const float4v*)&u.sx[ty + 1][c][tx4];
        float4v r1b = *(const float4v*)&u.sx[ty + 1][c][tx4 + 4];
        float4v r2a = *(const float4v*)&u.sx[ty + 2][c][tx4];
        float4v r2b = *(const float4v*)&u.sx[ty + 2][c][tx4 + 4];
        float S[6], D[6];
#pragma unroll
        for (int j = 0; j < 6; ++j) {
            float a0 = (j < 4) ? r0a[j] : r0b[j - 4];
            float a1v = (j < 4) ? r1a[j] : r1b[j - 4];
            float a2 = (j < 4) ? r2a[j] : r2b[j - 4];
            S[j] = fmaf(2.f, a1v, a0) + a2;
            D[j] = a2 - a0;
        }
#pragma unroll
        for (int r = 0; r < 4; ++r) {
            float cen = (r + 1 < 4) ? r1a[r + 1] : r1b[r - 3];
            float sxv = (S[r + 2] - S[r]) * 0.125f;
            float syv = (fmaf(2.f, D[r + 1], D[r]) + D[r + 2]) * 0.125f;
            float sy0 = __builtin_bit_cast(float, w1p[r]);
            w1p[r] = pack2(sy0, cen);
            w2p[r] = pack2(sxv, syv);
            cen1v[r] = cen;
        }
        if (cp == 1) {
            // c==3: begin-alive maxpool3 (zero-pad == -inf pad since x >= 0)
            unsigned int bits = 0;
#pragma unroll
            for (int r = 0; r < 4; ++r) {
                float m0 = -1.f;
#pragma unroll
                for (int j = 0; j < 3; ++j) {
                    float a0 = (r + j < 4) ? r0a[r + j] : r0b[r + j - 4];
                    float a1v = (r + j < 4) ? r1a[r + j] : r1b[r + j - 4];
                    float a2 = (r + j < 4) ? r2a[r + j] : r2b[r + j - 4];
                    m0 = fmaxf(m0, fmaxf(a0, fmaxf(a1v, a2)));
                }
                bits |= (m0 > 0.1f ? 1u : 0u) << (8 * r);
            }
            *(unsigned int*)(bm + (size_t)b * HW + (i0 + ty) * IMW + j0 + tx4) = bits;
        }
    }
    // xcT (XOR-swizzled on float-index bits 2..4; float4-aligned blocks)
    *(float4v*)&xcT[2 * cp][(4 * qd) ^ (((2 * cp) & 7) << 2)] = cen0v;
    *(float4v*)&xcT[2 * cp + 1][(4 * qd) ^ (((2 * cp + 1) & 7) << 2)] = cen1v;
    // ybuf: one b128 per pixel: physical group cp at swizzled slot (cp^sw).
    // 4th word: slots 8cp+6,7 -> cp==0 carries {bias=1.0, 0}; others zero (weights 0).
    {
        const unsigned int u3 = (cp == 0) ? 0x3F80u : 0u;
#pragma unroll
        for (int r = 0; r < 4; ++r) {
            const int p = 4 * qd + r;
            const int sw = p & 7;
            uint4v g = {w0p[r], w1p[r], w2p[r], u3};
            *(uint4v*)&((unsigned int*)&ybuf[p][0])[(cp ^ sw) << 2] = g;
        }
    }
    __syncthreads();

    // ---- per wave: GEMM1-T -> h scratch -> GEMM2 -> epilogue ----
    // nt = w + 4*half: within each half, the 4 waves cover 2 full rows (cols 0-15
    // and 16-31) => adjacent 64B store-halves are temporally paired -> L2 line merge.
    float* ob = out + (size_t)b * CN * HW;
    float* n3 = xn3 + (size_t)b * HW;
#pragma unroll
    for (int half = 0; half < 2; ++half) {
        const int nt  = w + 4 * half;
        const int row = 16 * nt + l15;
        const unsigned short* yr = &ybuf[row][0];
        const int rsw = row & 7;
        short8 y0 = *(const short8*)(yr + ((q ^ rsw) << 3));
        short8 y1 = *(const short8*)(yr + (((4 + q) ^ rsw) << 3));
        const int hsw = l15 & 7;
#pragma unroll
        for (int mi = 0; mi < 8; ++mi) {
            float4v acc = {};
            acc = __builtin_amdgcn_mfma_f32_16x16x32_bf16(a1[mi][0], y0, acc, 0, 0, 0);
            acc = __builtin_amdgcn_mfma_f32_16x16x32_bf16(a1[mi][1], y1, acc, 0, 0, 0);
            uint2v hp;
            hp[0] = pack2(fmaxf(acc[0], 0.f), fmaxf(acc[1], 0.f));
            hp[1] = pack2(fmaxf(acc[2], 0.f), fmaxf(acc[3], 0.f));
            // logical col 16mi+4q -> group 2mi+(q>>1), offset 4(q&1); XOR-swizzled
            *(uint2v*)&u.hb[w][l15][(((2 * mi + (q >> 1)) ^ hsw) << 3) + ((q & 1) << 2)] = hp;
        }
        float4v acc2 = {};
#pragma unroll
        for (int ks = 0; ks < 4; ++ks) {
            short8 hf = *(const short8*)&u.hb[w][l15][((4 * ks + q) ^ hsw) << 3];
            acc2 = __builtin_amdgcn_mfma_f32_16x16x32_bf16(hf, b2[ks], acc2, 0, 0, 0);
        }
        // epilogue: pixel p2 = 16nt+4q+r, channel = l15; 4 consecutive pixels -> dwordx4
        const int i  = i0 + (nt >> 1);
        const int jb = j0 + ((nt & 1) << 4) + (q << 2);
        float4v xc4 = *(const float4v*)&xcT[l15][(16 * nt + 4 * q) ^ ((l15 & 7) << 2)];
        float4v u4  = *(const float4v*)(ub + i * IMW + jb);
        float4v o;
#pragma unroll
        for (int r = 0; r < 4; ++r)
            o[r] = fmaf(acc2[r], (u4[r] <= 0.5f) ? 1.f : 0.f, xc4[r]);
        *(float4v*)(ob + l15 * HW + i * IMW + jb) = o;
        if (l15 == 3) *(float4v*)(n3 + i * IMW + jb) = o;
    }
}

// ---------------- Pass 2: alive masking ----------------
// alive = bm & (maxpool3(xn3) > 0.1); zero dead pixels (own pixel only).
// Full-row tiles (8x256), float4-staged.
__global__ __launch_bounds__(256) void nca_pass2(
    const float* __restrict__ xn3, const unsigned char* __restrict__ bm,
    float* __restrict__ out)
{
    __shared__ float s[10][264];           // data at col idx 4..259; halos at 3 and 260
    const int b   = blockIdx.z;
    const int i0  = blockIdx.y * 8;
    const int tid = threadIdx.x;
    const float* n3 = xn3 + (size_t)b * HW;

#pragma unroll
    for (int t = 0; t < 3; ++t) {
        const int idx = tid + 256 * t;     // 640 float4 slots: 10 rows x 64
        if (idx < 640) {
            const int r = idx >> 6, c4 = idx & 63;
            const int gi = i0 + r - 1;
            float4v vv;
            if ((unsigned)gi < IMH) vv = *(const float4v*)(n3 + gi * IMW + 4 * c4);
            else { vv[0] = vv[1] = vv[2] = vv[3] = -1e30f; }
            *(float4v*)&s[r][4 + 4 * c4] = vv;
        }
    }
    if (tid < 20) { const int r = tid >> 1; s[r][(tid & 1) ? 260 : 3] = -1e30f; }
    __syncthreads();

    const int c = tid;                     // column 0..255
    const unsigned char* bmb = bm + (size_t)b * HW + i0 * IMW + c;
    float* ob = out + (size_t)b * CN * HW;
#pragma unroll
    for (int r = 0; r < 8; ++r) {
        float m = fmaxf(fmaxf(fmaxf(s[r][c + 3], s[r][c + 4]), fmaxf(s[r][c + 5], s[r + 1][c + 3])),
                        fmaxf(fmaxf(s[r + 1][c + 4], s[r + 1][c + 5]),
                              fmaxf(fmaxf(s[r + 2][c + 3], s[r + 2][c + 4]), s[r + 2][c + 5])));
        if (!((m > 0.1f) && bmb[r * IMW])) {
            const int i = i0 + r;
#pragma unroll
            for (int ch = 0; ch < CN; ++ch)
                ob[ch * HW + i * IMW + c] = 0.f;
        }
    }
}

extern "C" void kernel_launch(void* const* d_in, const int* in_sizes, int n_in,
                              void* d_out, int out_size, void* d_ws, size_t ws_size,
                              hipStream_t stream) {
    const float* x   = (const float*)d_in[0];
    const float* upd = (const float*)d_in[1];
    const float* w1  = (const float*)d_in[2];
    const float* b1  = (const float*)d_in[3];
    const float* w2  = (const float*)d_in[4];
    float* out = (float*)d_out;

    char* ws = (char*)d_ws;
    float* xn3          = (float*)ws;                            // 8 MiB
    unsigned char* bmp  = (unsigned char*)(ws + (8u << 20));     // 2 MiB
    unsigned short* a1f = (unsigned short*)(ws + (10u << 20));   // 16 KiB
    unsigned short* b2f = a1f + 8192;                            // 4 KiB

    nca_prep<<<32, 256, 0, stream>>>(w1, b1, w2, a1f, b2f);
    nca_mfma<<<dim3(8, 64, 32), 256, 0, stream>>>(x, upd, a1f, b2f, out, xn3, bmp);
    nca_pass2<<<dim3(1, 32, 32), 256, 0, stream>>>(xn3, bmp, out);
}